// Round 3
// baseline (2118.281 us; speedup 1.0000x reference)
//
#include <hip/hip_runtime.h>
#include <math.h>

#define BB 8
#define HH 384
#define WW 384
#define NPAR 6
#define DEL 10
#define MAXIT 12
#define NACC 24
#define HWPIX (HH*WW)
#define NRT4 91                 // 4-row bands covering rows 10..373 exactly
#define NR2 8                   // staged I2 rows (iter tiles)
#define WINC 56                 // iter window cols (7 windows: 10..401, masked at 373)
#define NWIN 7
#define W_STG 68                // staging width = 56 + 12
#define PITCH2 69               // staged pitch
#define NJOB (NRT4*NWIN)        // 637 tiles
#define NGX 128                 // job-groups; block (g,b); 128*8 = 1024 blocks = 4/CU
#define NBLK_TOT (NGX*BB)
#define NR2F 6                  // k_final staged rows (2-row band)
#define PITCHF 141              // k_final staged pitch (140 used)
#define WSF 140                 // k_final staging width (128 + 12)
#define KB_ 8                   // atomic buckets (g & 7)
#define SPS 32                  // doubles per (bucket,b) slot (256 B, line-padded)

typedef float vf4 __attribute__((ext_vector_type(4)));
typedef vf4 uvf4 __attribute__((aligned(4)));      // 4B-aligned global dwordx4
typedef float f2v __attribute__((ext_vector_type(2), aligned(4)));
typedef float lf4 __attribute__((ext_vector_type(4)));  // 16B-aligned (LDS)

__device__ __forceinline__ vf4 ldv4(const float* p) { return *(const uvf4*)p; }

// One-instruction staged-pixel load: dwordx4 covering this pixel's 3 floats.
// Tail guard: last pixel uses a shifted load to avoid a 4B OOB read.
__device__ __forceinline__ lf4 ldpx3(const float* __restrict__ Ib, int pixoff) {
    const int fo = pixoff * 3;
    if (fo + 4 <= HWPIX * 3) {
        vf4 v = ldv4(Ib + fo);
        return (lf4){v.x, v.y, v.z, 0.f};
    }
    vf4 v = ldv4(Ib + fo - 1);
    return (lf4){v.y, v.z, v.w, 0.f};
}

__device__ __forceinline__ float cubicw(float s) {
    s = fabsf(s);
    float s2 = s * s, s3 = s2 * s;
    float w1 = 1.5f * s3 - 2.5f * s2 + 1.0f;
    float w2 = -0.5f * s3 + 2.5f * s2 - 4.0f * s + 2.0f;
    return (s <= 1.0f) ? w1 : ((s < 2.0f) ? w2 : 0.0f);
}

// global fast-path bicubic (taps guaranteed in-bounds; drift fallback)
__device__ __forceinline__ void bicubic3_fast(const float* __restrict__ Ib, double xg, double yg, float Iw[3]) {
    double fx = floor(xg), fy = floor(yg);
    float tx = (float)(xg - fx), ty = (float)(yg - fy);
    int xi = (int)fx, yi = (int)fy;
    float wx[4], wyv[4];
#pragma unroll
    for (int k = 0; k < 4; k++) { wx[k] = cubicw(tx - (float)(k - 1)); wyv[k] = cubicw(ty - (float)(k - 1)); }
    Iw[0] = 0.f; Iw[1] = 0.f; Iw[2] = 0.f;
    const float* base = Ib + (yi - 1) * (WW * 3) + (xi - 1) * 3;
#pragma unroll
    for (int j = 0; j < 4; j++) {
        const float* r = base + j * (WW * 3);
        vf4 v0 = ldv4(r), v1 = ldv4(r + 4), v2 = ldv4(r + 8);
        float r0 = fmaf(wx[0], v0.x, 0.f); r0 = fmaf(wx[1], v0.w, r0); r0 = fmaf(wx[2], v1.z, r0); r0 = fmaf(wx[3], v2.y, r0);
        float r1 = fmaf(wx[0], v0.y, 0.f); r1 = fmaf(wx[1], v1.x, r1); r1 = fmaf(wx[2], v1.w, r1); r1 = fmaf(wx[3], v2.z, r1);
        float r2 = fmaf(wx[0], v0.z, 0.f); r2 = fmaf(wx[1], v1.y, r2); r2 = fmaf(wx[2], v2.x, r2); r2 = fmaf(wx[3], v2.w, r2);
        Iw[0] = fmaf(wyv[j], r0, Iw[0]);
        Iw[1] = fmaf(wyv[j], r1, Iw[1]);
        Iw[2] = fmaf(wyv[j], r2, Iw[2]);
    }
}

// general bicubic with clip-to-edge (k_final_map fallback)
__device__ __forceinline__ void bicubic3_gen(const float* __restrict__ Ib, double xg, double yg, float Iw[3]) {
    double fx = floor(xg), fy = floor(yg);
    int xi = (int)fx, yi = (int)fy;
    float tx = (float)(xg - fx), ty = (float)(yg - fy);
    float wx[4], wyv[4];
    int xx[4], yy[4];
#pragma unroll
    for (int k = 0; k < 4; k++) {
        wx[k] = cubicw(tx - (float)(k - 1)); wyv[k] = cubicw(ty - (float)(k - 1));
        xx[k] = min(max(xi + k - 1, 0), WW - 1);
        yy[k] = min(max(yi + k - 1, 0), HH - 1);
    }
    Iw[0] = 0.f; Iw[1] = 0.f; Iw[2] = 0.f;
#pragma unroll
    for (int j = 0; j < 4; j++) {
        const float* row = Ib + yy[j] * (WW * 3);
        float r0 = 0.f, r1 = 0.f, r2 = 0.f;
#pragma unroll
        for (int k = 0; k < 4; k++) {
            const float* q = row + xx[k] * 3;
            r0 = fmaf(wx[k], q[0], r0); r1 = fmaf(wx[k], q[1], r1); r2 = fmaf(wx[k], q[2], r2);
        }
        Iw[0] = fmaf(wyv[j], r0, Iw[0]);
        Iw[1] = fmaf(wyv[j], r1, Iw[1]);
        Iw[2] = fmaf(wyv[j], r2, Iw[2]);
    }
}

// LDS bicubic from float4-padded staged tile (identical fma order); pitch param
template<int P>
__device__ __forceinline__ void bicubic3_lds(const lf4* __restrict__ T, int ssx, int ssy,
                                             float tx, float ty, float Iw[3]) {
    float wx[4], wyv[4];
#pragma unroll
    for (int k = 0; k < 4; k++) { wx[k] = cubicw(tx - (float)(k - 1)); wyv[k] = cubicw(ty - (float)(k - 1)); }
    Iw[0] = 0.f; Iw[1] = 0.f; Iw[2] = 0.f;
    const lf4* bp = T + (ssy - 1) * P + (ssx - 1);
#pragma unroll
    for (int j = 0; j < 4; j++) {
        lf4 t0 = bp[j * P + 0], t1 = bp[j * P + 1], t2 = bp[j * P + 2], t3 = bp[j * P + 3];
        float r0 = fmaf(wx[0], t0.x, 0.f); r0 = fmaf(wx[1], t1.x, r0); r0 = fmaf(wx[2], t2.x, r0); r0 = fmaf(wx[3], t3.x, r0);
        float r1 = fmaf(wx[0], t0.y, 0.f); r1 = fmaf(wx[1], t1.y, r1); r1 = fmaf(wx[2], t2.y, r1); r1 = fmaf(wx[3], t3.y, r1);
        float r2 = fmaf(wx[0], t0.z, 0.f); r2 = fmaf(wx[1], t1.z, r2); r2 = fmaf(wx[2], t2.z, r2); r2 = fmaf(wx[3], t3.z, r2);
        Iw[0] = fmaf(wyv[j], r0, Iw[0]);
        Iw[1] = fmaf(wyv[j], r1, Iw[1]);
        Iw[2] = fmaf(wyv[j], r2, Iw[2]);
    }
}

// Registers-only 6x6 SPD solve + affine compose. Fully unrolled Cholesky.
__device__ __forceinline__
void solve6_fast(const double* __restrict__ Sb, const double* __restrict__ pc,
                 double pn[6], int* convp) {
    const double b0 = Sb[0], b1 = Sb[3], b2 = Sb[1], b3 = Sb[2], b4 = Sb[4], b5 = Sb[5];
    const double h00 = Sb[6]  + 1e-6, h01 = Sb[12], h02 = Sb[7],  h03 = Sb[8],  h04 = Sb[13], h05 = Sb[14];
    const double h11 = Sb[18] + 1e-6, h12 = Sb[13], h13 = Sb[14], h14 = Sb[19], h15 = Sb[20];
    const double h22 = Sb[9]  + 1e-6, h23 = Sb[10], h24 = Sb[15], h25 = Sb[16];
    const double h33 = Sb[11] + 1e-6, h34 = Sb[16], h35 = Sb[17];
    const double h44 = Sb[21] + 1e-6, h45 = Sb[22];
    const double h55 = Sb[23] + 1e-6;

    const double l00 = sqrt(h00);
    const double i0 = 1.0 / l00;
    const double l10 = h01 * i0, l20 = h02 * i0, l30 = h03 * i0, l40 = h04 * i0, l50 = h05 * i0;
    const double l11 = sqrt(h11 - l10 * l10);
    const double i1 = 1.0 / l11;
    const double l21 = (h12 - l20 * l10) * i1;
    const double l31 = (h13 - l30 * l10) * i1;
    const double l41 = (h14 - l40 * l10) * i1;
    const double l51 = (h15 - l50 * l10) * i1;
    const double l22 = sqrt(h22 - l20 * l20 - l21 * l21);
    const double i2 = 1.0 / l22;
    const double l32 = (h23 - l30 * l20 - l31 * l21) * i2;
    const double l42 = (h24 - l40 * l20 - l41 * l21) * i2;
    const double l52 = (h25 - l50 * l20 - l51 * l21) * i2;
    const double l33 = sqrt(h33 - l30 * l30 - l31 * l31 - l32 * l32);
    const double i3 = 1.0 / l33;
    const double l43 = (h34 - l40 * l30 - l41 * l31 - l42 * l32) * i3;
    const double l53 = (h35 - l50 * l30 - l51 * l31 - l52 * l32) * i3;
    const double l44 = sqrt(h44 - l40 * l40 - l41 * l41 - l42 * l42 - l43 * l43);
    const double i4 = 1.0 / l44;
    const double l54 = (h45 - l50 * l40 - l51 * l41 - l52 * l42 - l53 * l43) * i4;
    const double l55 = sqrt(h55 - l50 * l50 - l51 * l51 - l52 * l52 - l53 * l53 - l54 * l54);
    const double i5 = 1.0 / l55;

    const double y0 = b0 * i0;
    const double y1 = (b1 - l10 * y0) * i1;
    const double y2 = (b2 - l20 * y0 - l21 * y1) * i2;
    const double y3 = (b3 - l30 * y0 - l31 * y1 - l32 * y2) * i3;
    const double y4 = (b4 - l40 * y0 - l41 * y1 - l42 * y2 - l43 * y3) * i4;
    const double y5 = (b5 - l50 * y0 - l51 * y1 - l52 * y2 - l53 * y3 - l54 * y4) * i5;

    const double d5 = y5 * i5;
    const double d4 = (y4 - l54 * d5) * i4;
    const double d3 = (y3 - l43 * d4 - l53 * d5) * i3;
    const double d2 = (y2 - l32 * d3 - l42 * d4 - l52 * d5) * i2;
    const double d1 = (y1 - l21 * d2 - l31 * d3 - l41 * d4 - l51 * d5) * i1;
    const double d0 = (y0 - l10 * d1 - l20 * d2 - l30 * d3 - l40 * d4 - l50 * d5) * i0;

    const double nrm = sqrt(d0*d0 + d1*d1 + d2*d2 + d3*d3 + d4*d4 + d5*d5);
    *convp = (nrm < 1e-3) ? 1 : 0;

    const double m00 = 1.0 + pc[2], m01 = pc[3], m02 = pc[0];
    const double m10 = pc[4], m11 = 1.0 + pc[5], m12 = pc[1];
    const double q00 = 1.0 + d2, q01 = d3, q02 = d0;
    const double q10 = d4, q11 = 1.0 + d5, q12 = d1;
    const double det = q00 * q11 - q01 * q10;
    const double j00 = q11 / det, j01 = -q01 / det;
    const double j10 = -q10 / det, j11 = q00 / det;
    const double jt0 = -(j00 * q02 + j01 * q12);
    const double jt1 = -(j10 * q02 + j11 * q12);
    const double n00 = m00 * j00 + m01 * j10;
    const double n01 = m00 * j01 + m01 * j11;
    const double n02 = m00 * jt0 + m01 * jt1 + m02;
    const double n10 = m10 * j00 + m11 * j10;
    const double n11 = m10 * j01 + m11 * j11;
    const double n12 = m10 * jt0 + m11 * jt1 + m12;
    pn[0] = n02;
    pn[1] = n12;
    pn[2] = n00 - 1.0;
    pn[3] = n01;
    pn[4] = n10;
    pn[5] = n11 - 1.0;
}

extern "C" __global__ __launch_bounds__(256)
void k_init(const float* __restrict__ p0, double* __restrict__ p_store,
            int* __restrict__ done0, double* __restrict__ S_part_all,
            double* __restrict__ Sf_part, unsigned int* __restrict__ arrive) {
    const int idx = blockIdx.x * 256 + threadIdx.x;
    const int n = MAXIT * KB_ * BB * SPS;          // 24576 doubles
    for (int i = idx; i < n; i += gridDim.x * 256) S_part_all[i] = 0.0;
    if (blockIdx.x == 0) {
        const int tid = threadIdx.x;
        if (tid < KB_ * BB * 4) Sf_part[tid] = 0.0;      // 256 doubles
        if (tid < BB * NPAR) p_store[tid] = (double)p0[tid];
        if (tid < BB) done0[tid] = 0;
        if (tid < 16) arrive[tid] = 0u;                  // grid-barrier counters
    }
}

// v4: PERSISTENT kernel — all 12 IC iterations in ONE dispatch. Rounds 0-2
// showed every pipe <25% busy; the cost was the serial 12-dispatch chain
// (launch ramp + L2 invalidation: 44 MB re-FETCH per dispatch). Grid 128x8 =
// 1024 blocks = 4/CU, co-residency GUARANTEED by __launch_bounds__(256,4)
// (VGPR<=128; round-2 body was 64) + 13.4 KB LDS (11/CU limit) -> software
// grid barrier is safe. Per iteration: spin on arrive[it-1] (agent acquire),
// reduce S buckets via agent-scope atomic loads (cross-XCD safe inside one
// kernel), redundant per-block Cholesky (deterministic -> all blocks of a b
// agree bitwise), compute 5 contiguous 4x56 tiles staged from CURRENT p,
// one bucketed f64-atomic set per block, release-arrive. Per-pixel math is
// byte-identical to the verified round-2 kernel.
extern "C" __global__ __launch_bounds__(256, 4)
void k_solve_all(const float* __restrict__ I1, const float* __restrict__ I2,
                 const float* __restrict__ p0, double* __restrict__ S_all,
                 double* __restrict__ p11_g, int* __restrict__ done11_g,
                 unsigned int* __restrict__ arrive) {
    // union: staged tile (8*69 lf4 = 8832 B) / reduction scratch (4*32*13 f64 = 13312 B)
    __shared__ __align__(16) double SMEMD[1664];
    __shared__ double Ssum[NACC];
    __shared__ double pbc[NPAR];
    __shared__ int dbc;
    lf4* SMEM = (lf4*)SMEMD;
    double* scr = SMEMD;
    const int tid = threadIdx.x;
    const int g = blockIdx.x;               // 0..127 job-group
    const int b = blockIdx.y;               // 0..7 batch
    const int wid = tid >> 6, lane = tid & 63;
    const int bkt = g & (KB_ - 1);
    const float* I1b = I1 + (size_t)b * HWPIX * 3;
    const float* I2b = I2 + (size_t)b * HWPIX * 3;

    if (tid == 0) {
#pragma unroll
        for (int i = 0; i < NPAR; i++) pbc[i] = (double)p0[b * NPAR + i];
        dbc = 0;
    }
    __syncthreads();

#pragma unroll 1
    for (int it = 0; it < MAXIT; ++it) {
        if (it > 0) {
            if (tid == 0) {
                while (__hip_atomic_load(&arrive[it - 1], __ATOMIC_ACQUIRE,
                                         __HIP_MEMORY_SCOPE_AGENT) < (unsigned)NBLK_TOT)
                    __builtin_amdgcn_s_sleep(8);
            }
            __syncthreads();
            if (!dbc) {
                if (tid < NACC) {
                    const double* Sp = S_all + (size_t)(it - 1) * KB_ * BB * SPS;
                    double a = 0.0;
#pragma unroll
                    for (int k = 0; k < KB_; k++)
                        a += __hip_atomic_load(&Sp[((size_t)(k * BB + b)) * SPS + tid],
                                               __ATOMIC_RELAXED, __HIP_MEMORY_SCOPE_AGENT);
                    Ssum[tid] = a;
                }
                __syncthreads();
                if (tid == 0) {
                    double pc[NPAR], pn[NPAR]; int conv;
#pragma unroll
                    for (int i = 0; i < NPAR; i++) pc[i] = pbc[i];
                    solve6_fast(Ssum, pc, pn, &conv);
#pragma unroll
                    for (int i = 0; i < NPAR; i++) pbc[i] = pn[i];
                    dbc = conv;
                }
                __syncthreads();
            }
        }
        if (it == MAXIT - 1 && g == 0 && tid == 0) {
#pragma unroll
            for (int i = 0; i < NPAR; i++) p11_g[b * NPAR + i] = pbc[i];
            done11_g[b] = dbc;
        }

        if (!dbc) {
            const double M00 = 1.0 + pbc[2], M01 = pbc[3], M02 = pbc[0];
            const double M10 = pbc[4], M11 = 1.0 + pbc[5], M12 = pbc[1];
            double acc = 0.0;               // tid<24 cross-tile accumulator

#pragma unroll 1
            for (int jj = 0; jj < 5; ++jj) {
                const int job = g * 5 + jj;             // contiguous jobs per block
                if (job >= NJOB) break;
                const int rt = job / NWIN, win = job - rt * NWIN;
                const int y0 = 10 + rt * 4;             // rows y0..y0+3 in [10,373]
                const int x0 = 10 + win * WINC;         // 10..346
                const int sx0 = x0 - 6;                 // >= 4

                // stage I2 rows (current p -> exact window)
                const double ygc = M10 * (double)(x0 + 28) + M11 * ((double)y0 + 1.5) + M12;
                const int r0 = (int)fmin(fmax(floor(ygc) - 3.0, -100000.0), 100000.0);
                for (int i = tid; i < NR2 * W_STG; i += 256) {
                    const int r = i / W_STG, c = i - r * W_STG;   // const divisor
                    const int gr = min(max(r0 + r, 0), HH - 1);
                    const int gc = min(sx0 + c, WW - 1);
                    SMEM[r * PITCH2 + c] = ldpx3(I2b, gr * WW + gc);
                }
                __syncthreads();

                // one pixel per lane (cols 0..55 active)
                const int y = y0 + wid;
                const double Y = (double)y;
                const double Bx = M01 * Y + M02;
                const double By = M11 * Y + M12;
                const int col = lane;
                const int x = x0 + col;
                const double X = (double)x;
                const double xg = fma(M00, X, Bx);
                const double yg = fma(M10, X, By);
                const double gx = rint(xg), gy = rint(yg);   // half-to-even
                const bool ok = (col < WINC) && (x < WW - DEL) &&
                                (gx >= (double)DEL && gx <= (double)(WW - DEL) &&
                                 gy >= (double)DEL && gy <= (double)(HH - DEL));
                const double fx = floor(xg), fy = floor(yg);
                const int xi = (int)fx, yi = (int)fy;
                const float tx = (float)(xg - fx), ty = (float)(yg - fy);
                const int sxi = xi - sx0, syi = yi - r0;
                const bool inwin = ok && (sxi >= 1) && (sxi <= W_STG - 3) &&
                                   (syi >= 1) && (syi <= NR2 - 3);

                float Iw[3];
                if (ok && !inwin) {
                    bicubic3_fast(I2b, xg, yg, Iw);   // rare drift fallback
                } else {
                    const int ssx = inwin ? sxi : 8;
                    const int ssy = inwin ? syi : 2;
                    bicubic3_lds<PITCH2>(SMEM, ssx, ssy, tx, ty, Iw);
                }

                // I1 neighborhood via coalesced global vector loads
                const int xc = min(x, WW - DEL - 1);
                const int pixL = y * WW + xc;
                const float* c = I1b + pixL * 3;
                vf4 u0 = ldv4(c - 3);          // cl0 cl1 cl2 c0
                vf4 u1 = ldv4(c + 1);          // c1 c2 cr0 cr1
                float cr2 = c[5];
                vf4 uu = ldv4(c - WW * 3);     // cu
                vf4 ud = ldv4(c + WW * 3);     // cd

                const float cl[3] = {u0.x, u0.y, u0.z};
                const float cv[3] = {u0.w, u1.x, u1.y};
                const float cr[3] = {u1.z, u1.w, cr2};
                const float cu[3] = {uu.x, uu.y, uu.z};
                const float cd[3] = {ud.x, ud.y, ud.z};

                const float msk = ok ? 1.0f : 0.0f;
                float Af = 0.f, Bf = 0.f, Cf = 0.f, T0f = 0.f, T1f = 0.f;
#pragma unroll
                for (int ch = 0; ch < 3; ch++) {
                    const float Ix = (cr[ch] - cl[ch]) * 0.5f;
                    const float Iy = (cd[ch] - cu[ch]) * 0.5f;
                    const float d = Iw[ch] - cv[ch];
                    const float u = d * 20.0f;
                    const float w = msk / sqrtf(fmaf(u, u, 1.0f));
                    const float wd = w * d;
                    T0f = fmaf(Ix, wd, T0f);
                    T1f = fmaf(Iy, wd, T1f);
                    const float wIx = w * Ix;
                    Af = fmaf(wIx, Ix, Af);
                    Bf = fmaf(wIx, Iy, Bf);
                    Cf = fmaf(w * Iy, Iy, Cf);
                }
                const double T0 = (double)T0f, T1 = (double)T1f;
                const double A = (double)Af, Bd = (double)Bf, Cd = (double)Cf;
                const double XX = X * X;
                double s[13];
                s[0] = T0;  s[1] = T0 * X;
                s[2] = T1;  s[3] = T1 * X;
                s[4] = A;   s[5] = A * X;   s[6] = A * XX;
                s[7] = Bd;  s[8] = Bd * X;  s[9] = Bd * XX;
                s[10] = Cd; s[11] = Cd * X; s[12] = Cd * XX;

#pragma unroll
                for (int i = 0; i < 13; i++) s[i] += __shfl_down(s[i], 32, 64);

                __syncthreads();             // staged-tile reads done; alias as scratch
                if (lane < 32) {
                    double* o = scr + ((size_t)(wid * 32 + lane)) * 13;
#pragma unroll
                    for (int i = 0; i < 13; i++) o[i] = s[i];
                }
                __syncthreads();

                if (tid < NACC) {
                    const unsigned long long CLO = 0x9787456454232010ULL;  // cix tid 0..15
                    const unsigned long long CHI = 0x00000000abcaba78ULL;  // cix tid 16..23
                    const unsigned long long YPW = 0x0000910910910410ULL;  // pw  tid 0..23
                    const int cix = (int)(((tid < 16) ? (CLO >> (tid * 4)) : (CHI >> ((tid - 16) * 4))) & 0xF);
                    const int pw  = (int)((YPW >> (tid * 2)) & 0x3);
                    for (int w = 0; w < 4; w++) {
                        const double* basep = scr + ((size_t)(w * 32)) * 13 + cix;
                        double part = 0.0;
                        for (int l = 0; l < 32; l++) part += basep[(size_t)l * 13];
                        const double Yw = (double)(y0 + w);
                        const double f = (pw == 0) ? 1.0 : ((pw == 1) ? Yw : Yw * Yw);
                        acc = fma(f, part, acc);
                    }
                }
                __syncthreads();             // scr reads done before next stage
            }

            if (tid < NACC)
                unsafeAtomicAdd(&S_all[(size_t)it * KB_ * BB * SPS +
                                       ((size_t)(bkt * BB + b)) * SPS + tid], acc);
        }

        if (it < MAXIT - 1) {
            __syncthreads();                 // wave0's atomics issued; all waves done
            if (tid == 0) {
                __threadfence();
                __hip_atomic_fetch_add(&arrive[it], 1u, __ATOMIC_RELEASE,
                                       __HIP_MEMORY_SCOPE_AGENT);
            }
        }
    }
}

// 2-row x 128-col tiles over the FULL image, ONE pixel per lane.
// 576x8 = 4608 blocks, 13.5 KB LDS -> 8 blocks/CU. Unchanged from round 2.
extern "C" __global__ __launch_bounds__(256, 8)
void k_final_map(const float* __restrict__ I1, const float* __restrict__ I2,
                 const double* __restrict__ p_in, const int* __restrict__ done_in,
                 const double* __restrict__ S_in, double* __restrict__ pf_g,
                 float* __restrict__ DI_out, float* __restrict__ Iw_out,
                 double* __restrict__ Sf_part) {
    __shared__ lf4 I2S[NR2F * PITCHF];      // 13536 B
    __shared__ double wsum[4][2];
    __shared__ double Ssum[NACC];
    __shared__ double pbc[NPAR];
    const int tid = threadIdx.x;
    const int b = blockIdx.y;
    const int tix = blockIdx.x;             // 0..575
    const int rt = tix / 3, win = tix - rt * 3;
    const int y0 = rt * 2;
    const int x0 = win * 128;
    const int sx0 = x0 - 6;

    // ---- staging from previous p (p11), issued before solve ----
    double pp[NPAR];
#pragma unroll
    for (int i = 0; i < NPAR; i++) pp[i] = p_in[b * NPAR + i];
    const double pM10 = pp[4], pM11 = 1.0 + pp[5], pM12 = pp[1];
    const double ygc = pM10 * (double)(x0 + 64) + pM11 * ((double)y0 + 0.5) + pM12;
    const int r0 = (int)fmin(fmax(floor(ygc) - 2.0, -100000.0), 100000.0);
    {
        const float* I2b = I2 + (size_t)b * HWPIX * 3;
        for (int i = tid; i < NR2F * WSF; i += 256) {
            const int r = i / WSF, c = i - r * WSF;
            const int gr = min(max(r0 + r, 0), HH - 1);    // clamped staging == clip-to-edge
            const int gc = min(max(sx0 + c, 0), WW - 1);
            I2S[r * PITCHF + c] = ldpx3(I2b, gr * WW + gc);
        }
    }
    if (tid < NACC) {
        double a0 = 0.0, a1 = 0.0;
#pragma unroll
        for (int k = 0; k < KB_; k += 2) {
            a0 += S_in[((size_t)(k * BB + b)) * SPS + tid];
            a1 += S_in[((size_t)((k + 1) * BB + b)) * SPS + tid];
        }
        Ssum[tid] = a0 + a1;
    }
    __syncthreads();
    if (tid == 0) {
        if (done_in[b]) {
#pragma unroll
            for (int i = 0; i < NPAR; i++) pbc[i] = pp[i];
        } else {
            double pn[6]; int conv;
            solve6_fast(Ssum, p_in + b * NPAR, pn, &conv);
#pragma unroll
            for (int i = 0; i < NPAR; i++) pbc[i] = pn[i];
        }
        if (blockIdx.x == 0) {
#pragma unroll
            for (int i = 0; i < NPAR; i++) pf_g[b * NPAR + i] = pbc[i];
        }
    }
    __syncthreads();

    const double M00 = 1.0 + pbc[2], M01 = pbc[3], M02 = pbc[0];
    const double M10 = pbc[4], M11 = 1.0 + pbc[5], M12 = pbc[1];
    const float* I1b = I1 + (size_t)b * HWPIX * 3;
    const float* I2b = I2 + (size_t)b * HWPIX * 3;
    float* DIb = DI_out + (size_t)b * HWPIX * 3;
    float* Iwb = Iw_out + (size_t)b * HWPIX * 3;

    const int row = tid >> 7;               // 0..1
    const int x = x0 + (tid & 127);
    const int y = y0 + row;
    const int pix = y * WW + x;

    const double X = (double)x, Yd = (double)y;
    const double xg = fma(M00, X, fma(M01, Yd, M02));
    const double yg = fma(M10, X, fma(M11, Yd, M12));
    const double fx = floor(xg), fy = floor(yg);
    const int xi = (int)fx, yi = (int)fy;
    const float tx = (float)(xg - fx), ty = (float)(yg - fy);
    const int sxi = xi - sx0, syi = yi - r0;
    const bool inwin = (sxi >= 1) && (sxi <= WSF - 3) && (syi >= 1) && (syi <= NR2F - 3);

    float Iwp[3];
    if (inwin) bicubic3_lds<PITCHF>(I2S, sxi, syi, tx, ty, Iwp);
    else       bicubic3_gen(I2b, xg, yg, Iwp);

    const bool v1 = (x >= DEL) && (x < WW - DEL) && (y >= DEL) && (y < HH - DEL);
    const double gx = rint(xg), gy = rint(yg);
    const bool wm = (gx >= (double)DEL && gx <= (double)(WW - DEL) &&
                     gy >= (double)DEL && gy <= (double)(HH - DEL));
    const bool mp = v1 && wm;

    // I1 center (12 B per lane, coalesced)
    const float* cbase = I1b + (size_t)pix * 3;
    const float cv0 = cbase[0], cv1 = cbase[1], cv2 = cbase[2];

    // Iw store (12 B per lane: dwordx2 + dword)
    {
        float* wp = Iwb + (size_t)pix * 3;
        *(f2v*)wp = (f2v){Iwp[0], Iwp[1]};
        wp[2] = Iwp[2];
    }
    double rho_s = 0.0, cnt_s = 0.0;
    {
        const float cvv[3] = {cv0, cv1, cv2};
        float dv[3];
#pragma unroll
        for (int ch = 0; ch < 3; ch++) {
            const float d1 = mp ? (Iwp[ch] - cvv[ch]) : 0.0f;
            dv[ch] = d1;
            if (mp) {
                const float u = d1 * 20.0f;
                rho_s += (double)(0.005f * (sqrtf(fmaf(u, u, 1.0f)) - 1.0f));
            }
        }
        if (mp) cnt_s += 3.0;
        float* dp_ = DIb + (size_t)pix * 3;
        *(f2v*)dp_ = (f2v){dv[0], dv[1]};
        dp_[2] = dv[2];
    }

#pragma unroll
    for (int off = 32; off >= 1; off >>= 1) {
        rho_s += __shfl_down(rho_s, off, 64);
        cnt_s += __shfl_down(cnt_s, off, 64);
    }
    const int wv = tid >> 6, lane = tid & 63;
    if (lane == 0) { wsum[wv][0] = rho_s; wsum[wv][1] = cnt_s; }
    __syncthreads();
    if (tid < 2) {
        double sv = wsum[0][tid] + wsum[1][tid] + wsum[2][tid] + wsum[3][tid];
        const int bkt = blockIdx.x & (KB_ - 1);
        unsafeAtomicAdd(&Sf_part[((size_t)(bkt * BB + b)) * 4 + tid], sv);
    }
}

extern "C" __global__ void k_finish(const double* __restrict__ p_fin,
                                    const double* __restrict__ Sf_part,
                                    float* __restrict__ out) {
    const int tid = threadIdx.x;  // 64 threads
    if (tid < BB * NPAR) out[tid] = (float)p_fin[tid];           // pf
    if (tid >= 48 && tid < 48 + BB) {
        const int b = tid - 48;
        double rs = 0.0, cs = 0.0;
#pragma unroll
        for (int k = 0; k < KB_; k++) {
            rs += Sf_part[((size_t)(k * BB + b)) * 4 + 0];
            cs += Sf_part[((size_t)(k * BB + b)) * 4 + 1];
        }
        out[48 + b] = (float)(rs / fmax(cs, 1.0));               // err
    }
}

extern "C" void kernel_launch(void* const* d_in, const int* in_sizes, int n_in,
                              void* d_out, int out_size, void* d_ws, size_t ws_size,
                              hipStream_t stream) {
    const float* I1 = (const float*)d_in[0];
    const float* I2 = (const float*)d_in[1];
    const float* p0 = (const float*)d_in[2];
    float* out = (float*)d_out;

    // ws layout (8B-aligned):
    // [0)      p_store    (MAXIT+1)*48 doubles = 4992 B   (p[11] at slot 11; p[12]=pf)
    // [4992)   done       (MAXIT+1)*8 ints     = 416 B
    // [5408)   S_part_all MAXIT*8*8*32 doubles = 196608 B (bucketed, line-padded)
    // [202016) Sf_part    8*8*4 doubles        = 2048 B
    // [204064) arrive     16 uints             = 64 B     (grid-barrier counters)
    double* p_store = (double*)d_ws;
    int* done_flags = (int*)((char*)d_ws + 4992);
    double* S_part_all = (double*)((char*)d_ws + 5408);
    double* Sf_part = (double*)((char*)d_ws + 202016);
    unsigned int* arrive = (unsigned int*)((char*)d_ws + 204064);

    k_init<<<32, 256, 0, stream>>>(p0, p_store, done_flags, S_part_all, Sf_part, arrive);

    const size_t SIT = (size_t)KB_ * BB * SPS;   // doubles per iteration
    dim3 gridS(NGX, BB), blkS(256);              // 1024 persistent blocks (4/CU)
    k_solve_all<<<gridS, blkS, 0, stream>>>(I1, I2, p0, S_part_all,
                                            p_store + (size_t)11 * BB * NPAR,
                                            done_flags + 11 * BB, arrive);

    // k_solve_all wrote p(11)/done(11); k_final_map computes p(12)=pf from buckets of it=11.
    float* DI_out = out + 56;
    float* Iw_out = out + 56 + (size_t)BB * HWPIX * 3;
    dim3 gridF(192 * 3, BB), blkF(256);          // 576 x 8 = 4608 blocks
    k_final_map<<<gridF, blkF, 0, stream>>>(I1, I2,
                                            p_store + (size_t)11 * BB * NPAR,
                                            done_flags + 11 * BB,
                                            S_part_all + (size_t)11 * SIT,
                                            p_store + (size_t)MAXIT * BB * NPAR,
                                            DI_out, Iw_out, Sf_part);
    k_finish<<<1, 64, 0, stream>>>(p_store + (size_t)MAXIT * BB * NPAR, Sf_part, out);
}

// Round 4
// 1525.823 us; speedup vs baseline: 1.3883x; 1.3883x over previous
//
#include <hip/hip_runtime.h>
#include <math.h>

#define BB 8
#define HH 384
#define WW 384
#define NPAR 6
#define DEL 10
#define MAXIT 12
#define NACC 24
#define HWPIX (HH*WW)
#define NRT4 91                 // 4-row bands covering rows 10..373 exactly
#define NR2 8                   // k_iter staged I2 rows
#define W_STG 76                // k_iter staging width = 64 + 12
#define PITCH2 77               // k_iter staged pitch
#define NWIN 6                  // k_iter 64-col windows (10..393, masked at 373)
#define NBX (NRT4*NWIN)         // 546 blocks.x
#define L1N 91                  // first-level counter lines (546 = 6*91)
#define L1CNT (6*BB)            // blocks per line (x-residue 6 x 8 batches)
#define NR2F 6                  // k_final staged rows (2-row band)
#define PITCHF 141              // k_final staged pitch (140 used)
#define WSF 140                 // k_final staging width (128 + 12)
#define KB_ 8                   // atomic buckets (blockIdx.x & 7)
#define SPS 32                  // doubles per (bucket,b) slot (256 B, line-padded)

typedef float vf4 __attribute__((ext_vector_type(4)));
typedef vf4 uvf4 __attribute__((aligned(4)));      // 4B-aligned global dwordx4
typedef float f2v __attribute__((ext_vector_type(2), aligned(4)));
typedef float lf4 __attribute__((ext_vector_type(4)));  // 16B-aligned (LDS)

__device__ __forceinline__ vf4 ldv4(const float* p) { return *(const uvf4*)p; }

// One-instruction staged-pixel load: dwordx4 covering this pixel's 3 floats.
// Tail guard: last pixel uses a shifted load to avoid a 4B OOB read.
__device__ __forceinline__ lf4 ldpx3(const float* __restrict__ Ib, int pixoff) {
    const int fo = pixoff * 3;
    if (fo + 4 <= HWPIX * 3) {
        vf4 v = ldv4(Ib + fo);
        return (lf4){v.x, v.y, v.z, 0.f};
    }
    vf4 v = ldv4(Ib + fo - 1);
    return (lf4){v.y, v.z, v.w, 0.f};
}

__device__ __forceinline__ float cubicw(float s) {
    s = fabsf(s);
    float s2 = s * s, s3 = s2 * s;
    float w1 = 1.5f * s3 - 2.5f * s2 + 1.0f;
    float w2 = -0.5f * s3 + 2.5f * s2 - 4.0f * s + 2.0f;
    return (s <= 1.0f) ? w1 : ((s < 2.0f) ? w2 : 0.0f);
}

// global fast-path bicubic (taps guaranteed in-bounds; drift fallback in k_iter)
__device__ __forceinline__ void bicubic3_fast(const float* __restrict__ Ib, double xg, double yg, float Iw[3]) {
    double fx = floor(xg), fy = floor(yg);
    float tx = (float)(xg - fx), ty = (float)(yg - fy);
    int xi = (int)fx, yi = (int)fy;
    float wx[4], wyv[4];
#pragma unroll
    for (int k = 0; k < 4; k++) { wx[k] = cubicw(tx - (float)(k - 1)); wyv[k] = cubicw(ty - (float)(k - 1)); }
    Iw[0] = 0.f; Iw[1] = 0.f; Iw[2] = 0.f;
    const float* base = Ib + (yi - 1) * (WW * 3) + (xi - 1) * 3;
#pragma unroll
    for (int j = 0; j < 4; j++) {
        const float* r = base + j * (WW * 3);
        vf4 v0 = ldv4(r), v1 = ldv4(r + 4), v2 = ldv4(r + 8);
        float r0 = fmaf(wx[0], v0.x, 0.f); r0 = fmaf(wx[1], v0.w, r0); r0 = fmaf(wx[2], v1.z, r0); r0 = fmaf(wx[3], v2.y, r0);
        float r1 = fmaf(wx[0], v0.y, 0.f); r1 = fmaf(wx[1], v1.x, r1); r1 = fmaf(wx[2], v1.w, r1); r1 = fmaf(wx[3], v2.z, r1);
        float r2 = fmaf(wx[0], v0.z, 0.f); r2 = fmaf(wx[1], v1.y, r2); r2 = fmaf(wx[2], v2.x, r2); r2 = fmaf(wx[3], v2.w, r2);
        Iw[0] = fmaf(wyv[j], r0, Iw[0]);
        Iw[1] = fmaf(wyv[j], r1, Iw[1]);
        Iw[2] = fmaf(wyv[j], r2, Iw[2]);
    }
}

// general bicubic with clip-to-edge (k_final_map fallback)
__device__ __forceinline__ void bicubic3_gen(const float* __restrict__ Ib, double xg, double yg, float Iw[3]) {
    double fx = floor(xg), fy = floor(yg);
    int xi = (int)fx, yi = (int)fy;
    float tx = (float)(xg - fx), ty = (float)(yg - fy);
    float wx[4], wyv[4];
    int xx[4], yy[4];
#pragma unroll
    for (int k = 0; k < 4; k++) {
        wx[k] = cubicw(tx - (float)(k - 1)); wyv[k] = cubicw(ty - (float)(k - 1));
        xx[k] = min(max(xi + k - 1, 0), WW - 1);
        yy[k] = min(max(yi + k - 1, 0), HH - 1);
    }
    Iw[0] = 0.f; Iw[1] = 0.f; Iw[2] = 0.f;
#pragma unroll
    for (int j = 0; j < 4; j++) {
        const float* row = Ib + yy[j] * (WW * 3);
        float r0 = 0.f, r1 = 0.f, r2 = 0.f;
#pragma unroll
        for (int k = 0; k < 4; k++) {
            const float* q = row + xx[k] * 3;
            r0 = fmaf(wx[k], q[0], r0); r1 = fmaf(wx[k], q[1], r1); r2 = fmaf(wx[k], q[2], r2);
        }
        Iw[0] = fmaf(wyv[j], r0, Iw[0]);
        Iw[1] = fmaf(wyv[j], r1, Iw[1]);
        Iw[2] = fmaf(wyv[j], r2, Iw[2]);
    }
}

// LDS bicubic from float4-padded staged tile (identical fma order); pitch param
template<int P>
__device__ __forceinline__ void bicubic3_lds(const lf4* __restrict__ T, int ssx, int ssy,
                                             float tx, float ty, float Iw[3]) {
    float wx[4], wyv[4];
#pragma unroll
    for (int k = 0; k < 4; k++) { wx[k] = cubicw(tx - (float)(k - 1)); wyv[k] = cubicw(ty - (float)(k - 1)); }
    Iw[0] = 0.f; Iw[1] = 0.f; Iw[2] = 0.f;
    const lf4* bp = T + (ssy - 1) * P + (ssx - 1);
#pragma unroll
    for (int j = 0; j < 4; j++) {
        lf4 t0 = bp[j * P + 0], t1 = bp[j * P + 1], t2 = bp[j * P + 2], t3 = bp[j * P + 3];
        float r0 = fmaf(wx[0], t0.x, 0.f); r0 = fmaf(wx[1], t1.x, r0); r0 = fmaf(wx[2], t2.x, r0); r0 = fmaf(wx[3], t3.x, r0);
        float r1 = fmaf(wx[0], t0.y, 0.f); r1 = fmaf(wx[1], t1.y, r1); r1 = fmaf(wx[2], t2.y, r1); r1 = fmaf(wx[3], t3.y, r1);
        float r2 = fmaf(wx[0], t0.z, 0.f); r2 = fmaf(wx[1], t1.z, r2); r2 = fmaf(wx[2], t2.z, r2); r2 = fmaf(wx[3], t3.z, r2);
        Iw[0] = fmaf(wyv[j], r0, Iw[0]);
        Iw[1] = fmaf(wyv[j], r1, Iw[1]);
        Iw[2] = fmaf(wyv[j], r2, Iw[2]);
    }
}

// Registers-only 6x6 SPD solve + affine compose. Fully unrolled Cholesky.
__device__ __forceinline__
void solve6_fast(const double* __restrict__ Sb, const double* __restrict__ pc,
                 double pn[6], int* convp) {
    const double b0 = Sb[0], b1 = Sb[3], b2 = Sb[1], b3 = Sb[2], b4 = Sb[4], b5 = Sb[5];
    const double h00 = Sb[6]  + 1e-6, h01 = Sb[12], h02 = Sb[7],  h03 = Sb[8],  h04 = Sb[13], h05 = Sb[14];
    const double h11 = Sb[18] + 1e-6, h12 = Sb[13], h13 = Sb[14], h14 = Sb[19], h15 = Sb[20];
    const double h22 = Sb[9]  + 1e-6, h23 = Sb[10], h24 = Sb[15], h25 = Sb[16];
    const double h33 = Sb[11] + 1e-6, h34 = Sb[16], h35 = Sb[17];
    const double h44 = Sb[21] + 1e-6, h45 = Sb[22];
    const double h55 = Sb[23] + 1e-6;

    const double l00 = sqrt(h00);
    const double i0 = 1.0 / l00;
    const double l10 = h01 * i0, l20 = h02 * i0, l30 = h03 * i0, l40 = h04 * i0, l50 = h05 * i0;
    const double l11 = sqrt(h11 - l10 * l10);
    const double i1 = 1.0 / l11;
    const double l21 = (h12 - l20 * l10) * i1;
    const double l31 = (h13 - l30 * l10) * i1;
    const double l41 = (h14 - l40 * l10) * i1;
    const double l51 = (h15 - l50 * l10) * i1;
    const double l22 = sqrt(h22 - l20 * l20 - l21 * l21);
    const double i2 = 1.0 / l22;
    const double l32 = (h23 - l30 * l20 - l31 * l21) * i2;
    const double l42 = (h24 - l40 * l20 - l41 * l21) * i2;
    const double l52 = (h25 - l50 * l20 - l51 * l21) * i2;
    const double l33 = sqrt(h33 - l30 * l30 - l31 * l31 - l32 * l32);
    const double i3 = 1.0 / l33;
    const double l43 = (h34 - l40 * l30 - l41 * l31 - l42 * l32) * i3;
    const double l53 = (h35 - l50 * l30 - l51 * l31 - l52 * l32) * i3;
    const double l44 = sqrt(h44 - l40 * l40 - l41 * l41 - l42 * l42 - l43 * l43);
    const double i4 = 1.0 / l44;
    const double l54 = (h45 - l50 * l40 - l51 * l41 - l52 * l42 - l53 * l43) * i4;
    const double l55 = sqrt(h55 - l50 * l50 - l51 * l51 - l52 * l52 - l53 * l53 - l54 * l54);
    const double i5 = 1.0 / l55;

    const double y0 = b0 * i0;
    const double y1 = (b1 - l10 * y0) * i1;
    const double y2 = (b2 - l20 * y0 - l21 * y1) * i2;
    const double y3 = (b3 - l30 * y0 - l31 * y1 - l32 * y2) * i3;
    const double y4 = (b4 - l40 * y0 - l41 * y1 - l42 * y2 - l43 * y3) * i4;
    const double y5 = (b5 - l50 * y0 - l51 * y1 - l52 * y2 - l53 * y3 - l54 * y4) * i5;

    const double d5 = y5 * i5;
    const double d4 = (y4 - l54 * d5) * i4;
    const double d3 = (y3 - l43 * d4 - l53 * d5) * i3;
    const double d2 = (y2 - l32 * d3 - l42 * d4 - l52 * d5) * i2;
    const double d1 = (y1 - l21 * d2 - l31 * d3 - l41 * d4 - l51 * d5) * i1;
    const double d0 = (y0 - l10 * d1 - l20 * d2 - l30 * d3 - l40 * d4 - l50 * d5) * i0;

    const double nrm = sqrt(d0*d0 + d1*d1 + d2*d2 + d3*d3 + d4*d4 + d5*d5);
    *convp = (nrm < 1e-3) ? 1 : 0;

    const double m00 = 1.0 + pc[2], m01 = pc[3], m02 = pc[0];
    const double m10 = pc[4], m11 = 1.0 + pc[5], m12 = pc[1];
    const double q00 = 1.0 + d2, q01 = d3, q02 = d0;
    const double q10 = d4, q11 = 1.0 + d5, q12 = d1;
    const double det = q00 * q11 - q01 * q10;
    const double j00 = q11 / det, j01 = -q01 / det;
    const double j10 = -q10 / det, j11 = q00 / det;
    const double jt0 = -(j00 * q02 + j01 * q12);
    const double jt1 = -(j10 * q02 + j11 * q12);
    const double n00 = m00 * j00 + m01 * j10;
    const double n01 = m00 * j01 + m01 * j11;
    const double n02 = m00 * jt0 + m01 * jt1 + m02;
    const double n10 = m10 * j00 + m11 * j10;
    const double n11 = m10 * j01 + m11 * j11;
    const double n12 = m10 * jt0 + m11 * jt1 + m12;
    pn[0] = n02;
    pn[1] = n12;
    pn[2] = n00 - 1.0;
    pn[3] = n01;
    pn[4] = n10;
    pn[5] = n11 - 1.0;
}

extern "C" __global__ __launch_bounds__(256)
void k_init(const float* __restrict__ p0, double* __restrict__ p_store,
            int* __restrict__ done0, double* __restrict__ S_part_all,
            double* __restrict__ Sf_part, unsigned int* __restrict__ cnt) {
    const int idx = blockIdx.x * 256 + threadIdx.x;
    const int n = MAXIT * KB_ * BB * SPS;          // 24576 doubles
    for (int i = idx; i < n; i += gridDim.x * 256) S_part_all[i] = 0.0;
    for (int i = idx; i < MAXIT * (L1N + 1); i += gridDim.x * 256) cnt[i] = 0u;
    if (blockIdx.x == 0) {
        const int tid = threadIdx.x;
        if (tid < KB_ * BB * 4) Sf_part[tid] = 0.0;      // 256 doubles
        if (tid < BB * NPAR) p_store[tid] = (double)p0[tid];
        if (tid < BB) done0[tid] = 0;
    }
}

// v5: round-2 multi-dispatch structure + LAST-BLOCK FINISHER. Round-3's
// persistent kernel proved spin-barriers are catastrophic here (agent-acquire
// polls invalidate the XCD L2 -> 289 MB refetch, VALUBusy 9%). Instead, each
// k_iter dispatch computes p[it+1] itself at its tail: hierarchical one-shot
// ACQ_REL counters (91 lines x 48 blocks -> 1 master) elect the LAST block,
// which sums the 8 S-buckets (relaxed agent atomic loads -- the round-3
// pattern that passed) and runs 8 parallel Choleskys writing p[it+1]/done[it+1].
// Every other block's prologue is now a 6-double scalar load instead of
// 192 f64 loads + a serial Cholesky (x4368 blocks). Per-pixel math is
// byte-identical to the verified round-2 kernel.
extern "C" __global__ __launch_bounds__(256, 8)
void k_iter(const float* __restrict__ I1, const float* __restrict__ I2,
            const double* __restrict__ p_in, const int* __restrict__ done_in,
            double* __restrict__ S_out, double* __restrict__ p_out,
            int* __restrict__ done_out, unsigned int* __restrict__ c1,
            unsigned int* __restrict__ c2) {
    // union: staged tile (8*77 lf4 = 9856 B) / reduction scratch (4*32*13 f64
    // = 13312 B) / finisher bucket sums (192 f64)
    __shared__ __align__(16) double SMEMD[1664];
    __shared__ int lastflag;
    lf4* SMEM = (lf4*)SMEMD;
    double* scr = SMEMD;
    const int tid = threadIdx.x;
    const int b = blockIdx.y;
    const int tix = blockIdx.x;             // 0..545
    const int dn = done_in[b];              // wave-uniform scalar load

    if (!dn) {
        const int rt = tix / NWIN, win = tix - rt * NWIN;
        const int y0 = 10 + rt * 4;             // rows y0..y0+3, all in [10,373]
        const int x0 = 10 + win * 64;           // 10,74,...,330 (win5 masked at 373)
        const int sx0 = x0 - 6;                 // >= 4

        double pp[NPAR];
#pragma unroll
        for (int i = 0; i < NPAR; i++) pp[i] = p_in[b * NPAR + i];   // uniform
        const double M00 = 1.0 + pp[2], M01 = pp[3], M02 = pp[0];
        const double M10 = pp[4], M11 = 1.0 + pp[5], M12 = pp[1];
        const float* I1b = I1 + (size_t)b * HWPIX * 3;
        const float* I2b = I2 + (size_t)b * HWPIX * 3;

        // stage I2 rows (current p -> exact window; fallback keeps it exact)
        const double ygc = M10 * (double)(x0 + 32) + M11 * ((double)y0 + 1.5) + M12;
        const int r0 = (int)fmin(fmax(floor(ygc) - 3.0, -100000.0), 100000.0);
        for (int i = tid; i < NR2 * W_STG; i += 256) {
            const int r = i / W_STG, c = i - r * W_STG;   // compile-time divisor
            const int gr = min(max(r0 + r, 0), HH - 1);
            const int gc = min(sx0 + c, WW - 1);
            SMEM[r * PITCH2 + c] = ldpx3(I2b, gr * WW + gc);
        }
        __syncthreads();

        // one pixel per lane
        const int wid = tid >> 6, lane = tid & 63;
        const int y = y0 + wid;                 // wave-uniform row, <= 373
        const double Y = (double)y;
        const double Bx = M01 * Y + M02;
        const double By = M11 * Y + M12;
        const int x = x0 + lane;
        const double X = (double)x;
        const double xg = fma(M00, X, Bx);
        const double yg = fma(M10, X, By);
        const double gx = rint(xg), gy = rint(yg);   // half-to-even like jnp.round
        const bool ok = (x < WW - DEL) &&
                        (gx >= (double)DEL && gx <= (double)(WW - DEL) &&
                         gy >= (double)DEL && gy <= (double)(HH - DEL));
        const double fx = floor(xg), fy = floor(yg);
        const int xi = (int)fx, yi = (int)fy;
        const float tx = (float)(xg - fx), ty = (float)(yg - fy);
        const int sxi = xi - sx0, syi = yi - r0;
        const bool inwin = ok && (sxi >= 1) && (sxi <= W_STG - 3) && (syi >= 1) && (syi <= NR2 - 3);

        float Iw[3];
        if (ok && !inwin) {
            bicubic3_fast(I2b, xg, yg, Iw);   // rare fallback
        } else {
            const int ssx = inwin ? sxi : 8;
            const int ssy = inwin ? syi : 2;
            bicubic3_lds<PITCH2>(SMEM, ssx, ssy, tx, ty, Iw);
        }

        // I1 neighborhood via coalesced global vector loads (interior-clamped)
        const int xc = min(x, WW - DEL - 1);
        const int pixL = y * WW + xc;
        const float* c = I1b + pixL * 3;
        vf4 u0 = ldv4(c - 3);          // cl0 cl1 cl2 c0
        vf4 u1 = ldv4(c + 1);          // c1 c2 cr0 cr1
        float cr2 = c[5];
        vf4 uu = ldv4(c - WW * 3);     // cu
        vf4 ud = ldv4(c + WW * 3);     // cd

        const float cl[3] = {u0.x, u0.y, u0.z};
        const float cv[3] = {u0.w, u1.x, u1.y};
        const float cr[3] = {u1.z, u1.w, cr2};
        const float cu[3] = {uu.x, uu.y, uu.z};
        const float cd[3] = {ud.x, ud.y, ud.z};

        const float msk = ok ? 1.0f : 0.0f;
        float Af = 0.f, Bf = 0.f, Cf = 0.f, T0f = 0.f, T1f = 0.f;
#pragma unroll
        for (int ch = 0; ch < 3; ch++) {
            const float Ix = (cr[ch] - cl[ch]) * 0.5f;
            const float Iy = (cd[ch] - cu[ch]) * 0.5f;
            const float d = Iw[ch] - cv[ch];
            const float u = d * 20.0f;
            const float w = msk / sqrtf(fmaf(u, u, 1.0f));
            const float wd = w * d;
            T0f = fmaf(Ix, wd, T0f);
            T1f = fmaf(Iy, wd, T1f);
            const float wIx = w * Ix;
            Af = fmaf(wIx, Ix, Af);
            Bf = fmaf(wIx, Iy, Bf);
            Cf = fmaf(w * Iy, Iy, Cf);
        }
        const double T0 = (double)T0f, T1 = (double)T1f;
        const double A = (double)Af, Bd = (double)Bf, Cd = (double)Cf;
        const double XX = X * X;
        double s[13];
        s[0] = T0;  s[1] = T0 * X;
        s[2] = T1;  s[3] = T1 * X;
        s[4] = A;   s[5] = A * X;   s[6] = A * XX;
        s[7] = Bd;  s[8] = Bd * X;  s[9] = Bd * XX;
        s[10] = Cd; s[11] = Cd * X; s[12] = Cd * XX;

#pragma unroll
        for (int i = 0; i < 13; i++) s[i] += __shfl_down(s[i], 32, 64);

        __syncthreads();                     // staged-tile reads done; alias as scratch
        if (lane < 32) {
            double* o = scr + ((size_t)(wid * 32 + lane)) * 13;
#pragma unroll
            for (int i = 0; i < 13; i++) o[i] = s[i];
        }
        __syncthreads();

        if (tid < NACC) {
            const unsigned long long CLO = 0x9787456454232010ULL;  // cix tid 0..15
            const unsigned long long CHI = 0x00000000abcaba78ULL;  // cix tid 16..23
            const unsigned long long YPW = 0x0000910910910410ULL;  // pw  tid 0..23
            const int cix = (int)(((tid < 16) ? (CLO >> (tid * 4)) : (CHI >> ((tid - 16) * 4))) & 0xF);
            const int pw  = (int)((YPW >> (tid * 2)) & 0x3);
            double acc = 0.0;
            for (int w = 0; w < 4; w++) {
                const double* basep = scr + ((size_t)(w * 32)) * 13 + cix;
                double part = 0.0;
                for (int l = 0; l < 32; l++) part += basep[(size_t)l * 13];
                const double Yw = (double)(y0 + w);
                const double f = (pw == 0) ? 1.0 : ((pw == 1) ? Yw : Yw * Yw);
                acc = fma(f, part, acc);
            }
            const int bkt = tix & (KB_ - 1);
            unsafeAtomicAdd(&S_out[((size_t)(bkt * BB + b)) * SPS + tid], acc);
        }
    }

    // ---- one-shot hierarchical arrival; unique last block finishes ----
    __syncthreads();                         // all bucket atomics issued; scr free
    if (tid == 0) {
        lastflag = 0;
        const unsigned o1 = __hip_atomic_fetch_add(&c1[tix % L1N], 1u,
                                __ATOMIC_ACQ_REL, __HIP_MEMORY_SCOPE_AGENT);
        if (o1 == (unsigned)(L1CNT - 1)) {
            const unsigned o2 = __hip_atomic_fetch_add(c2, 1u,
                                    __ATOMIC_ACQ_REL, __HIP_MEMORY_SCOPE_AGENT);
            if (o2 == (unsigned)(L1N - 1)) lastflag = 1;
        }
    }
    __syncthreads();
    if (lastflag) {
        double* FSUM = SMEMD;                // [8][24]
        if (tid < BB * NACC) {
            const int bt = tid / NACC, a = tid - bt * NACC;
            double sv = 0.0;
#pragma unroll
            for (int k = 0; k < KB_; k++)
                sv += __hip_atomic_load(&S_out[((size_t)(k * BB + bt)) * SPS + a],
                                        __ATOMIC_RELAXED, __HIP_MEMORY_SCOPE_AGENT);
            FSUM[bt * NACC + a] = sv;
        }
        __syncthreads();
        if (tid < BB) {
            const int bt = tid;
            double pc[NPAR], pn[NPAR];
#pragma unroll
            for (int i = 0; i < NPAR; i++) pc[i] = p_in[bt * NPAR + i];
            if (done_in[bt]) {
#pragma unroll
                for (int i = 0; i < NPAR; i++) p_out[bt * NPAR + i] = pc[i];
                done_out[bt] = 1;
            } else {
                int conv;
                solve6_fast(&FSUM[bt * NACC], pc, pn, &conv);
#pragma unroll
                for (int i = 0; i < NPAR; i++) p_out[bt * NPAR + i] = pn[i];
                done_out[bt] = conv;
            }
        }
    }
}

// 2-row x 128-col tiles over the FULL image, ONE pixel per lane.
// 576x8 = 4608 blocks, 13.5 KB LDS -> 8 blocks/CU. Prologue is now just a
// 6-double load of pf (computed by k_iter(11)'s finisher) -- the per-block
// Ssum+Cholesky is gone. Staging AND compute use the same pf (no drift).
extern "C" __global__ __launch_bounds__(256, 8)
void k_final_map(const float* __restrict__ I1, const float* __restrict__ I2,
                 const double* __restrict__ pf_in,
                 float* __restrict__ DI_out, float* __restrict__ Iw_out,
                 double* __restrict__ Sf_part) {
    __shared__ lf4 I2S[NR2F * PITCHF];      // 13536 B
    __shared__ double wsum[4][2];
    const int tid = threadIdx.x;
    const int b = blockIdx.y;
    const int tix = blockIdx.x;             // 0..575
    const int rt = tix / 3, win = tix - rt * 3;
    const int y0 = rt * 2;
    const int x0 = win * 128;
    const int sx0 = x0 - 6;

    double pp[NPAR];
#pragma unroll
    for (int i = 0; i < NPAR; i++) pp[i] = pf_in[b * NPAR + i];   // uniform
    const double M00 = 1.0 + pp[2], M01 = pp[3], M02 = pp[0];
    const double M10 = pp[4], M11 = 1.0 + pp[5], M12 = pp[1];
    const float* I1b = I1 + (size_t)b * HWPIX * 3;
    const float* I2b = I2 + (size_t)b * HWPIX * 3;
    float* DIb = DI_out + (size_t)b * HWPIX * 3;
    float* Iwb = Iw_out + (size_t)b * HWPIX * 3;

    const double ygc = M10 * (double)(x0 + 64) + M11 * ((double)y0 + 0.5) + M12;
    const int r0 = (int)fmin(fmax(floor(ygc) - 2.0, -100000.0), 100000.0);
    for (int i = tid; i < NR2F * WSF; i += 256) {
        const int r = i / WSF, c = i - r * WSF;
        const int gr = min(max(r0 + r, 0), HH - 1);    // clamped staging == clip-to-edge
        const int gc = min(max(sx0 + c, 0), WW - 1);
        I2S[r * PITCHF + c] = ldpx3(I2b, gr * WW + gc);
    }
    __syncthreads();

    const int row = tid >> 7;               // 0..1
    const int x = x0 + (tid & 127);
    const int y = y0 + row;
    const int pix = y * WW + x;

    const double X = (double)x, Yd = (double)y;
    const double xg = fma(M00, X, fma(M01, Yd, M02));
    const double yg = fma(M10, X, fma(M11, Yd, M12));
    const double fx = floor(xg), fy = floor(yg);
    const int xi = (int)fx, yi = (int)fy;
    const float tx = (float)(xg - fx), ty = (float)(yg - fy);
    const int sxi = xi - sx0, syi = yi - r0;
    const bool inwin = (sxi >= 1) && (sxi <= WSF - 3) && (syi >= 1) && (syi <= NR2F - 3);

    float Iwp[3];
    if (inwin) bicubic3_lds<PITCHF>(I2S, sxi, syi, tx, ty, Iwp);
    else       bicubic3_gen(I2b, xg, yg, Iwp);

    const bool v1 = (x >= DEL) && (x < WW - DEL) && (y >= DEL) && (y < HH - DEL);
    const double gx = rint(xg), gy = rint(yg);
    const bool wm = (gx >= (double)DEL && gx <= (double)(WW - DEL) &&
                     gy >= (double)DEL && gy <= (double)(HH - DEL));
    const bool mp = v1 && wm;

    // I1 center (12 B per lane, coalesced)
    const float* cbase = I1b + (size_t)pix * 3;
    const float cv0 = cbase[0], cv1 = cbase[1], cv2 = cbase[2];

    // Iw store (12 B per lane: dwordx2 + dword)
    {
        float* wp = Iwb + (size_t)pix * 3;
        *(f2v*)wp = (f2v){Iwp[0], Iwp[1]};
        wp[2] = Iwp[2];
    }
    double rho_s = 0.0, cnt_s = 0.0;
    {
        const float cvv[3] = {cv0, cv1, cv2};
        float dv[3];
#pragma unroll
        for (int ch = 0; ch < 3; ch++) {
            const float d1 = mp ? (Iwp[ch] - cvv[ch]) : 0.0f;
            dv[ch] = d1;
            if (mp) {
                const float u = d1 * 20.0f;
                rho_s += (double)(0.005f * (sqrtf(fmaf(u, u, 1.0f)) - 1.0f));
            }
        }
        if (mp) cnt_s += 3.0;
        float* dp_ = DIb + (size_t)pix * 3;
        *(f2v*)dp_ = (f2v){dv[0], dv[1]};
        dp_[2] = dv[2];
    }

#pragma unroll
    for (int off = 32; off >= 1; off >>= 1) {
        rho_s += __shfl_down(rho_s, off, 64);
        cnt_s += __shfl_down(cnt_s, off, 64);
    }
    const int wv = tid >> 6, lane = tid & 63;
    if (lane == 0) { wsum[wv][0] = rho_s; wsum[wv][1] = cnt_s; }
    __syncthreads();
    if (tid < 2) {
        double sv = wsum[0][tid] + wsum[1][tid] + wsum[2][tid] + wsum[3][tid];
        const int bkt = blockIdx.x & (KB_ - 1);
        unsafeAtomicAdd(&Sf_part[((size_t)(bkt * BB + b)) * 4 + tid], sv);
    }
}

extern "C" __global__ void k_finish(const double* __restrict__ p_fin,
                                    const double* __restrict__ Sf_part,
                                    float* __restrict__ out) {
    const int tid = threadIdx.x;  // 64 threads
    if (tid < BB * NPAR) out[tid] = (float)p_fin[tid];           // pf
    if (tid >= 48 && tid < 48 + BB) {
        const int b = tid - 48;
        double rs = 0.0, cs = 0.0;
#pragma unroll
        for (int k = 0; k < KB_; k++) {
            rs += Sf_part[((size_t)(k * BB + b)) * 4 + 0];
            cs += Sf_part[((size_t)(k * BB + b)) * 4 + 1];
        }
        out[48 + b] = (float)(rs / fmax(cs, 1.0));               // err
    }
}

extern "C" void kernel_launch(void* const* d_in, const int* in_sizes, int n_in,
                              void* d_out, int out_size, void* d_ws, size_t ws_size,
                              hipStream_t stream) {
    const float* I1 = (const float*)d_in[0];
    const float* I2 = (const float*)d_in[1];
    const float* p0 = (const float*)d_in[2];
    float* out = (float*)d_out;

    // ws layout (8B-aligned):
    // [0)      p_store    (MAXIT+1)*48 doubles = 4992 B   (p[it]; p[12]=pf)
    // [4992)   done       (MAXIT+1)*8 ints     = 416 B
    // [5408)   S_part_all MAXIT*8*8*32 doubles = 196608 B (bucketed, line-padded)
    // [202016) Sf_part    8*8*4 doubles        = 2048 B
    // [204064) cnt        MAXIT*(91+1) uints   = 4416 B   (arrival counters)
    double* p_store = (double*)d_ws;
    int* done_flags = (int*)((char*)d_ws + 4992);
    double* S_part_all = (double*)((char*)d_ws + 5408);
    double* Sf_part = (double*)((char*)d_ws + 202016);
    unsigned int* cnt = (unsigned int*)((char*)d_ws + 204064);

    k_init<<<32, 256, 0, stream>>>(p0, p_store, done_flags, S_part_all, Sf_part, cnt);

    const size_t SIT = (size_t)KB_ * BB * SPS;   // doubles per iteration
    dim3 gridI(NBX, BB), blkI(256);              // 546 x 8 = 4368 blocks
    for (int it = 0; it < MAXIT; it++) {
        k_iter<<<gridI, blkI, 0, stream>>>(I1, I2,
                                           p_store + (size_t)it * BB * NPAR,
                                           done_flags + it * BB,
                                           S_part_all + (size_t)it * SIT,
                                           p_store + (size_t)(it + 1) * BB * NPAR,
                                           done_flags + (it + 1) * BB,
                                           cnt + it * (L1N + 1),
                                           cnt + it * (L1N + 1) + L1N);
    }
    // k_iter(11)'s finisher wrote p_store[12] = pf.
    float* DI_out = out + 56;
    float* Iw_out = out + 56 + (size_t)BB * HWPIX * 3;
    dim3 gridF(192 * 3, BB), blkF(256);          // 576 x 8 = 4608 blocks
    k_final_map<<<gridF, blkF, 0, stream>>>(I1, I2,
                                            p_store + (size_t)MAXIT * BB * NPAR,
                                            DI_out, Iw_out, Sf_part);
    k_finish<<<1, 64, 0, stream>>>(p_store + (size_t)MAXIT * BB * NPAR, Sf_part, out);
}

// Round 5
// 705.439 us; speedup vs baseline: 3.0028x; 2.1629x over previous
//
#include <hip/hip_runtime.h>
#include <math.h>

#define BB 8
#define HH 384
#define WW 384
#define NPAR 6
#define DEL 10
#define MAXIT 12
#define NACC 24
#define HWPIX (HH*WW)
#define NRT4 91                 // 4-row bands covering rows 10..373 exactly
#define NR2 8                   // staged I2 rows (iter tiles)
#define WINC 56                 // iter window cols (7 windows: 10..401, masked at 373)
#define NWIN 7
#define W_STG 68                // staging width = 56 + 12
#define PITCH2 69               // staged pitch
#define NJOB (NRT4*NWIN)        // 637 tiles
#define NGX 128                 // job-groups; block (g,b); 128*8 = 1024 blocks = 4/CU
#define NLINE 64                // arrival lines (1024/16)
#define LQ 16                   // blocks per line
#define CNTS 65                 // u32 per iteration (64 lines + master)
#define NR2F 6                  // k_final staged rows (2-row band)
#define PITCHF 141              // k_final staged pitch (140 used)
#define WSF 140                 // k_final staging width (128 + 12)
#define KB_ 8                   // atomic buckets
#define SPS 32                  // doubles per (bucket,b) slot (256 B, line-padded)

typedef float vf4 __attribute__((ext_vector_type(4)));
typedef vf4 uvf4 __attribute__((aligned(4)));      // 4B-aligned global dwordx4
typedef float f2v __attribute__((ext_vector_type(2), aligned(4)));
typedef float lf4 __attribute__((ext_vector_type(4)));  // 16B-aligned (LDS)

__device__ __forceinline__ vf4 ldv4(const float* p) { return *(const uvf4*)p; }

// One-instruction staged-pixel load: dwordx4 covering this pixel's 3 floats.
// Tail guard: last pixel uses a shifted load to avoid a 4B OOB read.
__device__ __forceinline__ lf4 ldpx3(const float* __restrict__ Ib, int pixoff) {
    const int fo = pixoff * 3;
    if (fo + 4 <= HWPIX * 3) {
        vf4 v = ldv4(Ib + fo);
        return (lf4){v.x, v.y, v.z, 0.f};
    }
    vf4 v = ldv4(Ib + fo - 1);
    return (lf4){v.y, v.z, v.w, 0.f};
}

__device__ __forceinline__ float cubicw(float s) {
    s = fabsf(s);
    float s2 = s * s, s3 = s2 * s;
    float w1 = 1.5f * s3 - 2.5f * s2 + 1.0f;
    float w2 = -0.5f * s3 + 2.5f * s2 - 4.0f * s + 2.0f;
    return (s <= 1.0f) ? w1 : ((s < 2.0f) ? w2 : 0.0f);
}

// global fast-path bicubic (taps guaranteed in-bounds; drift fallback)
__device__ __forceinline__ void bicubic3_fast(const float* __restrict__ Ib, double xg, double yg, float Iw[3]) {
    double fx = floor(xg), fy = floor(yg);
    float tx = (float)(xg - fx), ty = (float)(yg - fy);
    int xi = (int)fx, yi = (int)fy;
    float wx[4], wyv[4];
#pragma unroll
    for (int k = 0; k < 4; k++) { wx[k] = cubicw(tx - (float)(k - 1)); wyv[k] = cubicw(ty - (float)(k - 1)); }
    Iw[0] = 0.f; Iw[1] = 0.f; Iw[2] = 0.f;
    const float* base = Ib + (yi - 1) * (WW * 3) + (xi - 1) * 3;
#pragma unroll
    for (int j = 0; j < 4; j++) {
        const float* r = base + j * (WW * 3);
        vf4 v0 = ldv4(r), v1 = ldv4(r + 4), v2 = ldv4(r + 8);
        float r0 = fmaf(wx[0], v0.x, 0.f); r0 = fmaf(wx[1], v0.w, r0); r0 = fmaf(wx[2], v1.z, r0); r0 = fmaf(wx[3], v2.y, r0);
        float r1 = fmaf(wx[0], v0.y, 0.f); r1 = fmaf(wx[1], v1.x, r1); r1 = fmaf(wx[2], v1.w, r1); r1 = fmaf(wx[3], v2.z, r1);
        float r2 = fmaf(wx[0], v0.z, 0.f); r2 = fmaf(wx[1], v1.y, r2); r2 = fmaf(wx[2], v2.x, r2); r2 = fmaf(wx[3], v2.w, r2);
        Iw[0] = fmaf(wyv[j], r0, Iw[0]);
        Iw[1] = fmaf(wyv[j], r1, Iw[1]);
        Iw[2] = fmaf(wyv[j], r2, Iw[2]);
    }
}

// general bicubic with clip-to-edge (k_final_map fallback)
__device__ __forceinline__ void bicubic3_gen(const float* __restrict__ Ib, double xg, double yg, float Iw[3]) {
    double fx = floor(xg), fy = floor(yg);
    int xi = (int)fx, yi = (int)fy;
    float tx = (float)(xg - fx), ty = (float)(yg - fy);
    float wx[4], wyv[4];
    int xx[4], yy[4];
#pragma unroll
    for (int k = 0; k < 4; k++) {
        wx[k] = cubicw(tx - (float)(k - 1)); wyv[k] = cubicw(ty - (float)(k - 1));
        xx[k] = min(max(xi + k - 1, 0), WW - 1);
        yy[k] = min(max(yi + k - 1, 0), HH - 1);
    }
    Iw[0] = 0.f; Iw[1] = 0.f; Iw[2] = 0.f;
#pragma unroll
    for (int j = 0; j < 4; j++) {
        const float* row = Ib + yy[j] * (WW * 3);
        float r0 = 0.f, r1 = 0.f, r2 = 0.f;
#pragma unroll
        for (int k = 0; k < 4; k++) {
            const float* q = row + xx[k] * 3;
            r0 = fmaf(wx[k], q[0], r0); r1 = fmaf(wx[k], q[1], r1); r2 = fmaf(wx[k], q[2], r2);
        }
        Iw[0] = fmaf(wyv[j], r0, Iw[0]);
        Iw[1] = fmaf(wyv[j], r1, Iw[1]);
        Iw[2] = fmaf(wyv[j], r2, Iw[2]);
    }
}

// LDS bicubic from float4-padded staged tile (identical fma order); pitch param
template<int P>
__device__ __forceinline__ void bicubic3_lds(const lf4* __restrict__ T, int ssx, int ssy,
                                             float tx, float ty, float Iw[3]) {
    float wx[4], wyv[4];
#pragma unroll
    for (int k = 0; k < 4; k++) { wx[k] = cubicw(tx - (float)(k - 1)); wyv[k] = cubicw(ty - (float)(k - 1)); }
    Iw[0] = 0.f; Iw[1] = 0.f; Iw[2] = 0.f;
    const lf4* bp = T + (ssy - 1) * P + (ssx - 1);
#pragma unroll
    for (int j = 0; j < 4; j++) {
        lf4 t0 = bp[j * P + 0], t1 = bp[j * P + 1], t2 = bp[j * P + 2], t3 = bp[j * P + 3];
        float r0 = fmaf(wx[0], t0.x, 0.f); r0 = fmaf(wx[1], t1.x, r0); r0 = fmaf(wx[2], t2.x, r0); r0 = fmaf(wx[3], t3.x, r0);
        float r1 = fmaf(wx[0], t0.y, 0.f); r1 = fmaf(wx[1], t1.y, r1); r1 = fmaf(wx[2], t2.y, r1); r1 = fmaf(wx[3], t3.y, r1);
        float r2 = fmaf(wx[0], t0.z, 0.f); r2 = fmaf(wx[1], t1.z, r2); r2 = fmaf(wx[2], t2.z, r2); r2 = fmaf(wx[3], t3.z, r2);
        Iw[0] = fmaf(wyv[j], r0, Iw[0]);
        Iw[1] = fmaf(wyv[j], r1, Iw[1]);
        Iw[2] = fmaf(wyv[j], r2, Iw[2]);
    }
}

// Registers-only 6x6 SPD solve + affine compose. Fully unrolled Cholesky.
__device__ __forceinline__
void solve6_fast(const double* __restrict__ Sb, const double* __restrict__ pc,
                 double pn[6], int* convp) {
    const double b0 = Sb[0], b1 = Sb[3], b2 = Sb[1], b3 = Sb[2], b4 = Sb[4], b5 = Sb[5];
    const double h00 = Sb[6]  + 1e-6, h01 = Sb[12], h02 = Sb[7],  h03 = Sb[8],  h04 = Sb[13], h05 = Sb[14];
    const double h11 = Sb[18] + 1e-6, h12 = Sb[13], h13 = Sb[14], h14 = Sb[19], h15 = Sb[20];
    const double h22 = Sb[9]  + 1e-6, h23 = Sb[10], h24 = Sb[15], h25 = Sb[16];
    const double h33 = Sb[11] + 1e-6, h34 = Sb[16], h35 = Sb[17];
    const double h44 = Sb[21] + 1e-6, h45 = Sb[22];
    const double h55 = Sb[23] + 1e-6;

    const double l00 = sqrt(h00);
    const double i0 = 1.0 / l00;
    const double l10 = h01 * i0, l20 = h02 * i0, l30 = h03 * i0, l40 = h04 * i0, l50 = h05 * i0;
    const double l11 = sqrt(h11 - l10 * l10);
    const double i1 = 1.0 / l11;
    const double l21 = (h12 - l20 * l10) * i1;
    const double l31 = (h13 - l30 * l10) * i1;
    const double l41 = (h14 - l40 * l10) * i1;
    const double l51 = (h15 - l50 * l10) * i1;
    const double l22 = sqrt(h22 - l20 * l20 - l21 * l21);
    const double i2 = 1.0 / l22;
    const double l32 = (h23 - l30 * l20 - l31 * l21) * i2;
    const double l42 = (h24 - l40 * l20 - l41 * l21) * i2;
    const double l52 = (h25 - l50 * l20 - l51 * l21) * i2;
    const double l33 = sqrt(h33 - l30 * l30 - l31 * l31 - l32 * l32);
    const double i3 = 1.0 / l33;
    const double l43 = (h34 - l40 * l30 - l41 * l31 - l42 * l32) * i3;
    const double l53 = (h35 - l50 * l30 - l51 * l31 - l52 * l32) * i3;
    const double l44 = sqrt(h44 - l40 * l40 - l41 * l41 - l42 * l42 - l43 * l43);
    const double i4 = 1.0 / l44;
    const double l54 = (h45 - l50 * l40 - l51 * l41 - l52 * l42 - l53 * l43) * i4;
    const double l55 = sqrt(h55 - l50 * l50 - l51 * l51 - l52 * l52 - l53 * l53 - l54 * l54);
    const double i5 = 1.0 / l55;

    const double y0 = b0 * i0;
    const double y1 = (b1 - l10 * y0) * i1;
    const double y2 = (b2 - l20 * y0 - l21 * y1) * i2;
    const double y3 = (b3 - l30 * y0 - l31 * y1 - l32 * y2) * i3;
    const double y4 = (b4 - l40 * y0 - l41 * y1 - l42 * y2 - l43 * y3) * i4;
    const double y5 = (b5 - l50 * y0 - l51 * y1 - l52 * y2 - l53 * y3 - l54 * y4) * i5;

    const double d5 = y5 * i5;
    const double d4 = (y4 - l54 * d5) * i4;
    const double d3 = (y3 - l43 * d4 - l53 * d5) * i3;
    const double d2 = (y2 - l32 * d3 - l42 * d4 - l52 * d5) * i2;
    const double d1 = (y1 - l21 * d2 - l31 * d3 - l41 * d4 - l51 * d5) * i1;
    const double d0 = (y0 - l10 * d1 - l20 * d2 - l30 * d3 - l40 * d4 - l50 * d5) * i0;

    const double nrm = sqrt(d0*d0 + d1*d1 + d2*d2 + d3*d3 + d4*d4 + d5*d5);
    *convp = (nrm < 1e-3) ? 1 : 0;

    const double m00 = 1.0 + pc[2], m01 = pc[3], m02 = pc[0];
    const double m10 = pc[4], m11 = 1.0 + pc[5], m12 = pc[1];
    const double q00 = 1.0 + d2, q01 = d3, q02 = d0;
    const double q10 = d4, q11 = 1.0 + d5, q12 = d1;
    const double det = q00 * q11 - q01 * q10;
    const double j00 = q11 / det, j01 = -q01 / det;
    const double j10 = -q10 / det, j11 = q00 / det;
    const double jt0 = -(j00 * q02 + j01 * q12);
    const double jt1 = -(j10 * q02 + j11 * q12);
    const double n00 = m00 * j00 + m01 * j10;
    const double n01 = m00 * j01 + m01 * j11;
    const double n02 = m00 * jt0 + m01 * jt1 + m02;
    const double n10 = m10 * j00 + m11 * j10;
    const double n11 = m10 * j01 + m11 * j11;
    const double n12 = m10 * jt0 + m11 * jt1 + m12;
    pn[0] = n02;
    pn[1] = n12;
    pn[2] = n00 - 1.0;
    pn[3] = n01;
    pn[4] = n10;
    pn[5] = n11 - 1.0;
}

extern "C" __global__ __launch_bounds__(256)
void k_init(double* __restrict__ S_part_all, double* __restrict__ Sf_part,
            unsigned int* __restrict__ cnt) {
    const int idx = blockIdx.x * 256 + threadIdx.x;
    const int n = MAXIT * KB_ * BB * SPS;          // 24576 doubles
    for (int i = idx; i < n; i += gridDim.x * 256) S_part_all[i] = 0.0;
    for (int i = idx; i < MAXIT * CNTS; i += gridDim.x * 256) cnt[i] = 0u;
    if (blockIdx.x == 0 && threadIdx.x < KB_ * BB * 4) Sf_part[threadIdx.x] = 0.0;
}

// v6: round-3 persistent structure with a FENCELESS barrier. Lessons from
// r3/r4: ANY agent-scope acquire/release (per-poll or per-block) emits L2
// inv/wbl2 on gfx950 -> µs-class serialized cache ops ruin everything. But
// no fences are NEEDED: S accumulation uses device-scope f64 RMWs that
// commit at the LLC, and readers use relaxed agent-scope atomic loads that
// bypass L2 and read the LLC directly. Ordering chain: each S-atomic's
// RETURNED old value is consumed (vmcnt retirement == RMW committed at LLC)
// -> __syncthreads -> relaxed hierarchical arrival RMWs (64 lines x 16 ->
// master) -> pollers spin with RELAXED loads + s_sleep. Zero cache
// maintenance; L2 (read-only I1/I2) stays warm across all 12 iterations.
// Per-pixel math byte-identical to the verified round-2/3 kernels.
extern "C" __global__ __launch_bounds__(256, 4)
void k_solve_all(const float* __restrict__ I1, const float* __restrict__ I2,
                 const float* __restrict__ p0, double* __restrict__ S_all,
                 double* __restrict__ pf_g, unsigned int* __restrict__ cnt) {
    // union: staged tile (8*69 lf4 = 8832 B) / reduction scratch (4*32*13 f64 = 13312 B)
    __shared__ __align__(16) double SMEMD[1664];
    __shared__ double Ssum[NACC];
    __shared__ double pbc[NPAR];
    __shared__ int dbc;
    lf4* SMEM = (lf4*)SMEMD;
    double* scr = SMEMD;
    const int tid = threadIdx.x;
    const int g = blockIdx.x;               // 0..127 job-group
    const int b = blockIdx.y;               // 0..7 batch
    const int wid = tid >> 6, lane = tid & 63;
    const int bkt = g & (KB_ - 1);
    const int fblk = b * NGX + g;           // flat block id 0..1023
    const float* I1b = I1 + (size_t)b * HWPIX * 3;
    const float* I2b = I2 + (size_t)b * HWPIX * 3;

    if (tid == 0) {
#pragma unroll
        for (int i = 0; i < NPAR; i++) pbc[i] = (double)p0[b * NPAR + i];
        dbc = 0;
    }
    __syncthreads();

#pragma unroll 1
    for (int it = 0; it < MAXIT; ++it) {
        // ---- compute this iteration's S contribution ----
        if (!dbc) {
            const double M00 = 1.0 + pbc[2], M01 = pbc[3], M02 = pbc[0];
            const double M10 = pbc[4], M11 = 1.0 + pbc[5], M12 = pbc[1];
            double acc = 0.0;               // tid<24 cross-tile accumulator

#pragma unroll 1
            for (int jj = 0; jj < 5; ++jj) {
                const int job = g * 5 + jj;             // contiguous jobs per block
                if (job >= NJOB) break;
                const int rt = job / NWIN, win = job - rt * NWIN;
                const int y0 = 10 + rt * 4;             // rows y0..y0+3 in [10,373]
                const int x0 = 10 + win * WINC;         // 10..346
                const int sx0 = x0 - 6;                 // >= 4

                // stage I2 rows (current p -> exact window)
                const double ygc = M10 * (double)(x0 + 28) + M11 * ((double)y0 + 1.5) + M12;
                const int r0 = (int)fmin(fmax(floor(ygc) - 3.0, -100000.0), 100000.0);
                for (int i = tid; i < NR2 * W_STG; i += 256) {
                    const int r = i / W_STG, c = i - r * W_STG;   // const divisor
                    const int gr = min(max(r0 + r, 0), HH - 1);
                    const int gc = min(sx0 + c, WW - 1);
                    SMEM[r * PITCH2 + c] = ldpx3(I2b, gr * WW + gc);
                }
                __syncthreads();

                // one pixel per lane (cols 0..55 active)
                const int y = y0 + wid;
                const double Y = (double)y;
                const double Bx = M01 * Y + M02;
                const double By = M11 * Y + M12;
                const int col = lane;
                const int x = x0 + col;
                const double X = (double)x;
                const double xg = fma(M00, X, Bx);
                const double yg = fma(M10, X, By);
                const double gx = rint(xg), gy = rint(yg);   // half-to-even
                const bool ok = (col < WINC) && (x < WW - DEL) &&
                                (gx >= (double)DEL && gx <= (double)(WW - DEL) &&
                                 gy >= (double)DEL && gy <= (double)(HH - DEL));
                const double fx = floor(xg), fy = floor(yg);
                const int xi = (int)fx, yi = (int)fy;
                const float tx = (float)(xg - fx), ty = (float)(yg - fy);
                const int sxi = xi - sx0, syi = yi - r0;
                const bool inwin = ok && (sxi >= 1) && (sxi <= W_STG - 3) &&
                                   (syi >= 1) && (syi <= NR2 - 3);

                float Iw[3];
                if (ok && !inwin) {
                    bicubic3_fast(I2b, xg, yg, Iw);   // rare drift fallback
                } else {
                    const int ssx = inwin ? sxi : 8;
                    const int ssy = inwin ? syi : 2;
                    bicubic3_lds<PITCH2>(SMEM, ssx, ssy, tx, ty, Iw);
                }

                // I1 neighborhood via coalesced global vector loads
                const int xc = min(x, WW - DEL - 1);
                const int pixL = y * WW + xc;
                const float* c = I1b + pixL * 3;
                vf4 u0 = ldv4(c - 3);          // cl0 cl1 cl2 c0
                vf4 u1 = ldv4(c + 1);          // c1 c2 cr0 cr1
                float cr2 = c[5];
                vf4 uu = ldv4(c - WW * 3);     // cu
                vf4 ud = ldv4(c + WW * 3);     // cd

                const float cl[3] = {u0.x, u0.y, u0.z};
                const float cv[3] = {u0.w, u1.x, u1.y};
                const float cr[3] = {u1.z, u1.w, cr2};
                const float cu[3] = {uu.x, uu.y, uu.z};
                const float cd[3] = {ud.x, ud.y, ud.z};

                const float msk = ok ? 1.0f : 0.0f;
                float Af = 0.f, Bf = 0.f, Cf = 0.f, T0f = 0.f, T1f = 0.f;
#pragma unroll
                for (int ch = 0; ch < 3; ch++) {
                    const float Ix = (cr[ch] - cl[ch]) * 0.5f;
                    const float Iy = (cd[ch] - cu[ch]) * 0.5f;
                    const float d = Iw[ch] - cv[ch];
                    const float u = d * 20.0f;
                    const float w = msk / sqrtf(fmaf(u, u, 1.0f));
                    const float wd = w * d;
                    T0f = fmaf(Ix, wd, T0f);
                    T1f = fmaf(Iy, wd, T1f);
                    const float wIx = w * Ix;
                    Af = fmaf(wIx, Ix, Af);
                    Bf = fmaf(wIx, Iy, Bf);
                    Cf = fmaf(w * Iy, Iy, Cf);
                }
                const double T0 = (double)T0f, T1 = (double)T1f;
                const double A = (double)Af, Bd = (double)Bf, Cd = (double)Cf;
                const double XX = X * X;
                double s[13];
                s[0] = T0;  s[1] = T0 * X;
                s[2] = T1;  s[3] = T1 * X;
                s[4] = A;   s[5] = A * X;   s[6] = A * XX;
                s[7] = Bd;  s[8] = Bd * X;  s[9] = Bd * XX;
                s[10] = Cd; s[11] = Cd * X; s[12] = Cd * XX;

#pragma unroll
                for (int i = 0; i < 13; i++) s[i] += __shfl_down(s[i], 32, 64);

                __syncthreads();             // staged-tile reads done; alias as scratch
                if (lane < 32) {
                    double* o = scr + ((size_t)(wid * 32 + lane)) * 13;
#pragma unroll
                    for (int i = 0; i < 13; i++) o[i] = s[i];
                }
                __syncthreads();

                if (tid < NACC) {
                    const unsigned long long CLO = 0x9787456454232010ULL;  // cix tid 0..15
                    const unsigned long long CHI = 0x00000000abcaba78ULL;  // cix tid 16..23
                    const unsigned long long YPW = 0x0000910910910410ULL;  // pw  tid 0..23
                    const int cix = (int)(((tid < 16) ? (CLO >> (tid * 4)) : (CHI >> ((tid - 16) * 4))) & 0xF);
                    const int pw  = (int)((YPW >> (tid * 2)) & 0x3);
                    for (int w = 0; w < 4; w++) {
                        const double* basep = scr + ((size_t)(w * 32)) * 13 + cix;
                        double part = 0.0;
                        for (int l = 0; l < 32; l++) part += basep[(size_t)l * 13];
                        const double Yw = (double)(y0 + w);
                        const double f = (pw == 0) ? 1.0 : ((pw == 1) ? Yw : Yw * Yw);
                        acc = fma(f, part, acc);
                    }
                }
                __syncthreads();             // scr reads done before next stage
            }

            if (tid < NACC) {
                // returning form: consuming the old value forces vmcnt
                // retirement == RMW committed at the LLC before we arrive.
                double oldv = unsafeAtomicAdd(&S_all[(size_t)it * KB_ * BB * SPS +
                                        ((size_t)(bkt * BB + b)) * SPS + tid], acc);
                asm volatile("" :: "v"(oldv));
            }
        }

        // ---- fenceless grid barrier #it (all relaxed, LLC-homed) ----
        __syncthreads();                     // all S RMWs of this block committed
        if (tid == 0) {
            unsigned int* c1 = cnt + it * CNTS;
            unsigned int* cm = c1 + NLINE;
            const unsigned o1 = __hip_atomic_fetch_add(&c1[fblk >> 4], 1u,
                                    __ATOMIC_RELAXED, __HIP_MEMORY_SCOPE_AGENT);
            if (o1 == (unsigned)(LQ - 1)) {
                const unsigned o2 = __hip_atomic_fetch_add(cm, 1u,
                                        __ATOMIC_RELAXED, __HIP_MEMORY_SCOPE_AGENT);
                asm volatile("" :: "v"(o2));
            }
            while (__hip_atomic_load(cm, __ATOMIC_RELAXED,
                                     __HIP_MEMORY_SCOPE_AGENT) < (unsigned)NLINE)
                __builtin_amdgcn_s_sleep(16);
        }
        __syncthreads();                     // S_all[it] complete for ALL blocks

        // ---- solve p[it+1] (redundant per block; relaxed LLC atomic loads) ----
        if (!dbc) {
            if (tid < NACC) {
                const double* Sp = S_all + (size_t)it * KB_ * BB * SPS;
                double a = 0.0;
#pragma unroll
                for (int k = 0; k < KB_; k++)
                    a += __hip_atomic_load(&Sp[((size_t)(k * BB + b)) * SPS + tid],
                                           __ATOMIC_RELAXED, __HIP_MEMORY_SCOPE_AGENT);
                Ssum[tid] = a;
            }
            __syncthreads();
            if (tid == 0) {
                double pc[NPAR], pn[NPAR]; int conv;
#pragma unroll
                for (int i = 0; i < NPAR; i++) pc[i] = pbc[i];
                solve6_fast(Ssum, pc, pn, &conv);
#pragma unroll
                for (int i = 0; i < NPAR; i++) pbc[i] = pn[i];
                dbc = conv;
            }
            __syncthreads();
        }
    }

    // pbc now holds pf = p[12] (frozen at convergence); publish once.
    if (g == 0 && tid == 0) {
#pragma unroll
        for (int i = 0; i < NPAR; i++) pf_g[b * NPAR + i] = pbc[i];
    }
}

// 2-row x 128-col tiles over the FULL image, ONE pixel per lane.
// 576x8 = 4608 blocks, 13.5 KB LDS -> 8 blocks/CU. Prologue-free: reads pf.
extern "C" __global__ __launch_bounds__(256, 8)
void k_final_map(const float* __restrict__ I1, const float* __restrict__ I2,
                 const double* __restrict__ pf_in,
                 float* __restrict__ DI_out, float* __restrict__ Iw_out,
                 double* __restrict__ Sf_part) {
    __shared__ lf4 I2S[NR2F * PITCHF];      // 13536 B
    __shared__ double wsum[4][2];
    const int tid = threadIdx.x;
    const int b = blockIdx.y;
    const int tix = blockIdx.x;             // 0..575
    const int rt = tix / 3, win = tix - rt * 3;
    const int y0 = rt * 2;
    const int x0 = win * 128;
    const int sx0 = x0 - 6;

    double pp[NPAR];
#pragma unroll
    for (int i = 0; i < NPAR; i++) pp[i] = pf_in[b * NPAR + i];   // uniform
    const double M00 = 1.0 + pp[2], M01 = pp[3], M02 = pp[0];
    const double M10 = pp[4], M11 = 1.0 + pp[5], M12 = pp[1];
    const float* I1b = I1 + (size_t)b * HWPIX * 3;
    const float* I2b = I2 + (size_t)b * HWPIX * 3;
    float* DIb = DI_out + (size_t)b * HWPIX * 3;
    float* Iwb = Iw_out + (size_t)b * HWPIX * 3;

    const double ygc = M10 * (double)(x0 + 64) + M11 * ((double)y0 + 0.5) + M12;
    const int r0 = (int)fmin(fmax(floor(ygc) - 2.0, -100000.0), 100000.0);
    for (int i = tid; i < NR2F * WSF; i += 256) {
        const int r = i / WSF, c = i - r * WSF;
        const int gr = min(max(r0 + r, 0), HH - 1);    // clamped staging == clip-to-edge
        const int gc = min(max(sx0 + c, 0), WW - 1);
        I2S[r * PITCHF + c] = ldpx3(I2b, gr * WW + gc);
    }
    __syncthreads();

    const int row = tid >> 7;               // 0..1
    const int x = x0 + (tid & 127);
    const int y = y0 + row;
    const int pix = y * WW + x;

    const double X = (double)x, Yd = (double)y;
    const double xg = fma(M00, X, fma(M01, Yd, M02));
    const double yg = fma(M10, X, fma(M11, Yd, M12));
    const double fx = floor(xg), fy = floor(yg);
    const int xi = (int)fx, yi = (int)fy;
    const float tx = (float)(xg - fx), ty = (float)(yg - fy);
    const int sxi = xi - sx0, syi = yi - r0;
    const bool inwin = (sxi >= 1) && (sxi <= WSF - 3) && (syi >= 1) && (syi <= NR2F - 3);

    float Iwp[3];
    if (inwin) bicubic3_lds<PITCHF>(I2S, sxi, syi, tx, ty, Iwp);
    else       bicubic3_gen(I2b, xg, yg, Iwp);

    const bool v1 = (x >= DEL) && (x < WW - DEL) && (y >= DEL) && (y < HH - DEL);
    const double gx = rint(xg), gy = rint(yg);
    const bool wm = (gx >= (double)DEL && gx <= (double)(WW - DEL) &&
                     gy >= (double)DEL && gy <= (double)(HH - DEL));
    const bool mp = v1 && wm;

    // I1 center (12 B per lane, coalesced)
    const float* cbase = I1b + (size_t)pix * 3;
    const float cv0 = cbase[0], cv1 = cbase[1], cv2 = cbase[2];

    // Iw store (12 B per lane: dwordx2 + dword)
    {
        float* wp = Iwb + (size_t)pix * 3;
        *(f2v*)wp = (f2v){Iwp[0], Iwp[1]};
        wp[2] = Iwp[2];
    }
    double rho_s = 0.0, cnt_s = 0.0;
    {
        const float cvv[3] = {cv0, cv1, cv2};
        float dv[3];
#pragma unroll
        for (int ch = 0; ch < 3; ch++) {
            const float d1 = mp ? (Iwp[ch] - cvv[ch]) : 0.0f;
            dv[ch] = d1;
            if (mp) {
                const float u = d1 * 20.0f;
                rho_s += (double)(0.005f * (sqrtf(fmaf(u, u, 1.0f)) - 1.0f));
            }
        }
        if (mp) cnt_s += 3.0;
        float* dp_ = DIb + (size_t)pix * 3;
        *(f2v*)dp_ = (f2v){dv[0], dv[1]};
        dp_[2] = dv[2];
    }

#pragma unroll
    for (int off = 32; off >= 1; off >>= 1) {
        rho_s += __shfl_down(rho_s, off, 64);
        cnt_s += __shfl_down(cnt_s, off, 64);
    }
    const int wv = tid >> 6, lane = tid & 63;
    if (lane == 0) { wsum[wv][0] = rho_s; wsum[wv][1] = cnt_s; }
    __syncthreads();
    if (tid < 2) {
        double sv = wsum[0][tid] + wsum[1][tid] + wsum[2][tid] + wsum[3][tid];
        const int bkt = blockIdx.x & (KB_ - 1);
        unsafeAtomicAdd(&Sf_part[((size_t)(bkt * BB + b)) * 4 + tid], sv);
    }
}

extern "C" __global__ void k_finish(const double* __restrict__ p_fin,
                                    const double* __restrict__ Sf_part,
                                    float* __restrict__ out) {
    const int tid = threadIdx.x;  // 64 threads
    if (tid < BB * NPAR) out[tid] = (float)p_fin[tid];           // pf
    if (tid >= 48 && tid < 48 + BB) {
        const int b = tid - 48;
        double rs = 0.0, cs = 0.0;
#pragma unroll
        for (int k = 0; k < KB_; k++) {
            rs += Sf_part[((size_t)(k * BB + b)) * 4 + 0];
            cs += Sf_part[((size_t)(k * BB + b)) * 4 + 1];
        }
        out[48 + b] = (float)(rs / fmax(cs, 1.0));               // err
    }
}

extern "C" void kernel_launch(void* const* d_in, const int* in_sizes, int n_in,
                              void* d_out, int out_size, void* d_ws, size_t ws_size,
                              hipStream_t stream) {
    const float* I1 = (const float*)d_in[0];
    const float* I2 = (const float*)d_in[1];
    const float* p0 = (const float*)d_in[2];
    float* out = (float*)d_out;

    // ws layout (8B-aligned):
    // [0)      p_store    (MAXIT+1)*48 doubles = 4992 B   (only slot 12 = pf used)
    // [4992)   done       (MAXIT+1)*8 ints     = 416 B    (unused, layout kept)
    // [5408)   S_part_all MAXIT*8*8*32 doubles = 196608 B (bucketed, line-padded)
    // [202016) Sf_part    8*8*4 doubles        = 2048 B
    // [204064) cnt        MAXIT*65 uints       = 3120 B   (barrier counters)
    double* p_store = (double*)d_ws;
    double* S_part_all = (double*)((char*)d_ws + 5408);
    double* Sf_part = (double*)((char*)d_ws + 202016);
    unsigned int* cnt = (unsigned int*)((char*)d_ws + 204064);
    double* pf = p_store + (size_t)MAXIT * BB * NPAR;

    k_init<<<32, 256, 0, stream>>>(S_part_all, Sf_part, cnt);

    dim3 gridS(NGX, BB), blkS(256);              // 1024 persistent blocks (4/CU)
    k_solve_all<<<gridS, blkS, 0, stream>>>(I1, I2, p0, S_part_all, pf, cnt);

    float* DI_out = out + 56;
    float* Iw_out = out + 56 + (size_t)BB * HWPIX * 3;
    dim3 gridF(192 * 3, BB), blkF(256);          // 576 x 8 = 4608 blocks
    k_final_map<<<gridF, blkF, 0, stream>>>(I1, I2, pf, DI_out, Iw_out, Sf_part);
    k_finish<<<1, 64, 0, stream>>>(pf, Sf_part, out);
}

// Round 6
// 427.580 us; speedup vs baseline: 4.9541x; 1.6498x over previous
//
#include <hip/hip_runtime.h>
#include <math.h>

#define BB 8
#define HH 384
#define WW 384
#define NPAR 6
#define DEL 10
#define MAXIT 12
#define NACC 24
#define HWPIX (HH*WW)
#define NRT4 91                 // 4-row bands covering rows 10..373 exactly
#define NWIN 6                  // 64-col windows (10..393, masked at 373)
#define NBX (NRT4*NWIN)         // 546 blocks.x
#define L1N 91                  // first-level counter lines (546 = 6*91)
#define L1CNT (6*BB)            // blocks per line (x-residue 6 x 8 batches)
#define CNTS 92                 // u32 per iteration (91 lines + master)
#define NR2F 6                  // k_final staged rows (2-row band)
#define PITCHF 141              // k_final staged pitch (140 used)
#define WSF 140                 // k_final staging width (128 + 12)
#define KB_ 8                   // atomic buckets (blockIdx.x & 7)
#define SPS 32                  // doubles per (bucket,b) slot (256 B, line-padded)

typedef float vf4 __attribute__((ext_vector_type(4)));
typedef vf4 uvf4 __attribute__((aligned(4)));      // 4B-aligned global dwordx4
typedef float f2v __attribute__((ext_vector_type(2), aligned(4)));
typedef float lf4 __attribute__((ext_vector_type(4)));  // 16B-aligned (LDS)

__device__ __forceinline__ vf4 ldv4(const float* p) { return *(const uvf4*)p; }

// One-instruction staged-pixel load: dwordx4 covering this pixel's 3 floats.
// Tail guard: last pixel uses a shifted load to avoid a 4B OOB read.
__device__ __forceinline__ lf4 ldpx3(const float* __restrict__ Ib, int pixoff) {
    const int fo = pixoff * 3;
    if (fo + 4 <= HWPIX * 3) {
        vf4 v = ldv4(Ib + fo);
        return (lf4){v.x, v.y, v.z, 0.f};
    }
    vf4 v = ldv4(Ib + fo - 1);
    return (lf4){v.y, v.z, v.w, 0.f};
}

__device__ __forceinline__ float cubicw(float s) {
    s = fabsf(s);
    float s2 = s * s, s3 = s2 * s;
    float w1 = 1.5f * s3 - 2.5f * s2 + 1.0f;
    float w2 = -0.5f * s3 + 2.5f * s2 - 4.0f * s + 2.0f;
    return (s <= 1.0f) ? w1 : ((s < 2.0f) ? w2 : 0.0f);
}

// direct-global bicubic; taps guaranteed in-bounds for k_iter 'ok' pixels and
// k_final interior pixels. fma order identical to the old LDS path (bit-exact).
__device__ __forceinline__ void bicubic3_fast(const float* __restrict__ Ib, double xg, double yg, float Iw[3]) {
    double fx = floor(xg), fy = floor(yg);
    float tx = (float)(xg - fx), ty = (float)(yg - fy);
    int xi = (int)fx, yi = (int)fy;
    float wx[4], wyv[4];
#pragma unroll
    for (int k = 0; k < 4; k++) { wx[k] = cubicw(tx - (float)(k - 1)); wyv[k] = cubicw(ty - (float)(k - 1)); }
    Iw[0] = 0.f; Iw[1] = 0.f; Iw[2] = 0.f;
    const float* base = Ib + (yi - 1) * (WW * 3) + (xi - 1) * 3;
#pragma unroll
    for (int j = 0; j < 4; j++) {
        const float* r = base + j * (WW * 3);
        vf4 v0 = ldv4(r), v1 = ldv4(r + 4), v2 = ldv4(r + 8);
        float r0 = fmaf(wx[0], v0.x, 0.f); r0 = fmaf(wx[1], v0.w, r0); r0 = fmaf(wx[2], v1.z, r0); r0 = fmaf(wx[3], v2.y, r0);
        float r1 = fmaf(wx[0], v0.y, 0.f); r1 = fmaf(wx[1], v1.x, r1); r1 = fmaf(wx[2], v1.w, r1); r1 = fmaf(wx[3], v2.z, r1);
        float r2 = fmaf(wx[0], v0.z, 0.f); r2 = fmaf(wx[1], v1.y, r2); r2 = fmaf(wx[2], v2.x, r2); r2 = fmaf(wx[3], v2.w, r2);
        Iw[0] = fmaf(wyv[j], r0, Iw[0]);
        Iw[1] = fmaf(wyv[j], r1, Iw[1]);
        Iw[2] = fmaf(wyv[j], r2, Iw[2]);
    }
}

// general bicubic with clip-to-edge (k_final_map edge pixels)
__device__ __forceinline__ void bicubic3_gen(const float* __restrict__ Ib, double xg, double yg, float Iw[3]) {
    double fx = floor(xg), fy = floor(yg);
    int xi = (int)fx, yi = (int)fy;
    float tx = (float)(xg - fx), ty = (float)(yg - fy);
    float wx[4], wyv[4];
    int xx[4], yy[4];
#pragma unroll
    for (int k = 0; k < 4; k++) {
        wx[k] = cubicw(tx - (float)(k - 1)); wyv[k] = cubicw(ty - (float)(k - 1));
        xx[k] = min(max(xi + k - 1, 0), WW - 1);
        yy[k] = min(max(yi + k - 1, 0), HH - 1);
    }
    Iw[0] = 0.f; Iw[1] = 0.f; Iw[2] = 0.f;
#pragma unroll
    for (int j = 0; j < 4; j++) {
        const float* row = Ib + yy[j] * (WW * 3);
        float r0 = 0.f, r1 = 0.f, r2 = 0.f;
#pragma unroll
        for (int k = 0; k < 4; k++) {
            const float* q = row + xx[k] * 3;
            r0 = fmaf(wx[k], q[0], r0); r1 = fmaf(wx[k], q[1], r1); r2 = fmaf(wx[k], q[2], r2);
        }
        Iw[0] = fmaf(wyv[j], r0, Iw[0]);
        Iw[1] = fmaf(wyv[j], r1, Iw[1]);
        Iw[2] = fmaf(wyv[j], r2, Iw[2]);
    }
}

// LDS bicubic from float4-padded staged tile (identical fma order); pitch param
template<int P>
__device__ __forceinline__ void bicubic3_lds(const lf4* __restrict__ T, int ssx, int ssy,
                                             float tx, float ty, float Iw[3]) {
    float wx[4], wyv[4];
#pragma unroll
    for (int k = 0; k < 4; k++) { wx[k] = cubicw(tx - (float)(k - 1)); wyv[k] = cubicw(ty - (float)(k - 1)); }
    Iw[0] = 0.f; Iw[1] = 0.f; Iw[2] = 0.f;
    const lf4* bp = T + (ssy - 1) * P + (ssx - 1);
#pragma unroll
    for (int j = 0; j < 4; j++) {
        lf4 t0 = bp[j * P + 0], t1 = bp[j * P + 1], t2 = bp[j * P + 2], t3 = bp[j * P + 3];
        float r0 = fmaf(wx[0], t0.x, 0.f); r0 = fmaf(wx[1], t1.x, r0); r0 = fmaf(wx[2], t2.x, r0); r0 = fmaf(wx[3], t3.x, r0);
        float r1 = fmaf(wx[0], t0.y, 0.f); r1 = fmaf(wx[1], t1.y, r1); r1 = fmaf(wx[2], t2.y, r1); r1 = fmaf(wx[3], t3.y, r1);
        float r2 = fmaf(wx[0], t0.z, 0.f); r2 = fmaf(wx[1], t1.z, r2); r2 = fmaf(wx[2], t2.z, r2); r2 = fmaf(wx[3], t3.z, r2);
        Iw[0] = fmaf(wyv[j], r0, Iw[0]);
        Iw[1] = fmaf(wyv[j], r1, Iw[1]);
        Iw[2] = fmaf(wyv[j], r2, Iw[2]);
    }
}

// Registers-only 6x6 SPD solve + affine compose. Fully unrolled Cholesky.
__device__ __forceinline__
void solve6_fast(const double* __restrict__ Sb, const double* __restrict__ pc,
                 double pn[6], int* convp) {
    const double b0 = Sb[0], b1 = Sb[3], b2 = Sb[1], b3 = Sb[2], b4 = Sb[4], b5 = Sb[5];
    const double h00 = Sb[6]  + 1e-6, h01 = Sb[12], h02 = Sb[7],  h03 = Sb[8],  h04 = Sb[13], h05 = Sb[14];
    const double h11 = Sb[18] + 1e-6, h12 = Sb[13], h13 = Sb[14], h14 = Sb[19], h15 = Sb[20];
    const double h22 = Sb[9]  + 1e-6, h23 = Sb[10], h24 = Sb[15], h25 = Sb[16];
    const double h33 = Sb[11] + 1e-6, h34 = Sb[16], h35 = Sb[17];
    const double h44 = Sb[21] + 1e-6, h45 = Sb[22];
    const double h55 = Sb[23] + 1e-6;

    const double l00 = sqrt(h00);
    const double i0 = 1.0 / l00;
    const double l10 = h01 * i0, l20 = h02 * i0, l30 = h03 * i0, l40 = h04 * i0, l50 = h05 * i0;
    const double l11 = sqrt(h11 - l10 * l10);
    const double i1 = 1.0 / l11;
    const double l21 = (h12 - l20 * l10) * i1;
    const double l31 = (h13 - l30 * l10) * i1;
    const double l41 = (h14 - l40 * l10) * i1;
    const double l51 = (h15 - l50 * l10) * i1;
    const double l22 = sqrt(h22 - l20 * l20 - l21 * l21);
    const double i2 = 1.0 / l22;
    const double l32 = (h23 - l30 * l20 - l31 * l21) * i2;
    const double l42 = (h24 - l40 * l20 - l41 * l21) * i2;
    const double l52 = (h25 - l50 * l20 - l51 * l21) * i2;
    const double l33 = sqrt(h33 - l30 * l30 - l31 * l31 - l32 * l32);
    const double i3 = 1.0 / l33;
    const double l43 = (h34 - l40 * l30 - l41 * l31 - l42 * l32) * i3;
    const double l53 = (h35 - l50 * l30 - l51 * l31 - l52 * l32) * i3;
    const double l44 = sqrt(h44 - l40 * l40 - l41 * l41 - l42 * l42 - l43 * l43);
    const double i4 = 1.0 / l44;
    const double l54 = (h45 - l50 * l40 - l51 * l41 - l52 * l42 - l53 * l43) * i4;
    const double l55 = sqrt(h55 - l50 * l50 - l51 * l51 - l52 * l52 - l53 * l53 - l54 * l54);
    const double i5 = 1.0 / l55;

    const double y0 = b0 * i0;
    const double y1 = (b1 - l10 * y0) * i1;
    const double y2 = (b2 - l20 * y0 - l21 * y1) * i2;
    const double y3 = (b3 - l30 * y0 - l31 * y1 - l32 * y2) * i3;
    const double y4 = (b4 - l40 * y0 - l41 * y1 - l42 * y2 - l43 * y3) * i4;
    const double y5 = (b5 - l50 * y0 - l51 * y1 - l52 * y2 - l53 * y3 - l54 * y4) * i5;

    const double d5 = y5 * i5;
    const double d4 = (y4 - l54 * d5) * i4;
    const double d3 = (y3 - l43 * d4 - l53 * d5) * i3;
    const double d2 = (y2 - l32 * d3 - l42 * d4 - l52 * d5) * i2;
    const double d1 = (y1 - l21 * d2 - l31 * d3 - l41 * d4 - l51 * d5) * i1;
    const double d0 = (y0 - l10 * d1 - l20 * d2 - l30 * d3 - l40 * d4 - l50 * d5) * i0;

    const double nrm = sqrt(d0*d0 + d1*d1 + d2*d2 + d3*d3 + d4*d4 + d5*d5);
    *convp = (nrm < 1e-3) ? 1 : 0;

    const double m00 = 1.0 + pc[2], m01 = pc[3], m02 = pc[0];
    const double m10 = pc[4], m11 = 1.0 + pc[5], m12 = pc[1];
    const double q00 = 1.0 + d2, q01 = d3, q02 = d0;
    const double q10 = d4, q11 = 1.0 + d5, q12 = d1;
    const double det = q00 * q11 - q01 * q10;
    const double j00 = q11 / det, j01 = -q01 / det;
    const double j10 = -q10 / det, j11 = q00 / det;
    const double jt0 = -(j00 * q02 + j01 * q12);
    const double jt1 = -(j10 * q02 + j11 * q12);
    const double n00 = m00 * j00 + m01 * j10;
    const double n01 = m00 * j01 + m01 * j11;
    const double n02 = m00 * jt0 + m01 * jt1 + m02;
    const double n10 = m10 * j00 + m11 * j10;
    const double n11 = m10 * j01 + m11 * j11;
    const double n12 = m10 * jt0 + m11 * jt1 + m12;
    pn[0] = n02;
    pn[1] = n12;
    pn[2] = n00 - 1.0;
    pn[3] = n01;
    pn[4] = n10;
    pn[5] = n11 - 1.0;
}

extern "C" __global__ __launch_bounds__(256)
void k_init(const float* __restrict__ p0, double* __restrict__ p_store,
            int* __restrict__ done0, double* __restrict__ S_part_all,
            double* __restrict__ Sf_part, unsigned int* __restrict__ cnt) {
    const int idx = blockIdx.x * 256 + threadIdx.x;
    const int n = MAXIT * KB_ * BB * SPS;          // 24576 doubles
    for (int i = idx; i < n; i += gridDim.x * 256) S_part_all[i] = 0.0;
    for (int i = idx; i < MAXIT * CNTS; i += gridDim.x * 256) cnt[i] = 0u;
    if (blockIdx.x == 0) {
        const int tid = threadIdx.x;
        if (tid < KB_ * BB * 4) Sf_part[tid] = 0.0;      // 256 doubles
        if (tid < BB * NPAR) p_store[tid] = (double)p0[tid];
        if (tid < BB) done0[tid] = 0;
    }
}

// v7: multi-dispatch + DIRECT-GLOBAL bicubic (no I2 staging) + RELAXED
// last-block finisher. Rationale: latency-bound regime (VALUBusy<=31%
// everywhere); staging cost ~1550 loads + sync + LDS that caps occupancy,
// while for every 'ok' pixel bicubic3_fast's taps are provably in-bounds
// (gx,gy in [10,374] -> taps in [8,376]) and tap cachelines are shared by
// neighboring lanes (L1/L2 reuse). LDS is now only the 13.3 KB reduction
// scratch -> 8 blocks/CU at VGPR<=64. Finisher = R4 structure with RELAXED
// counters (R4's ACQ_REL was the poison: per-block L2 wbl2/inv; R5 validated
// relaxed RMW + returning-S-atomic + relaxed LLC loads end-to-end).
extern "C" __global__ __launch_bounds__(256, 8)
void k_iter(const float* __restrict__ I1, const float* __restrict__ I2,
            const double* __restrict__ p_in, const int* __restrict__ done_in,
            double* __restrict__ S_out, double* __restrict__ p_out,
            int* __restrict__ done_out, unsigned int* __restrict__ c1,
            unsigned int* __restrict__ c2) {
    // scratch: 4 waves x 32 lanes x 13 f64 = 13312 B; finisher FSUM aliases it
    __shared__ __align__(16) double SMEMD[1664];
    __shared__ int lastflag;
    double* scr = SMEMD;
    const int tid = threadIdx.x;
    const int b = blockIdx.y;
    const int tix = blockIdx.x;             // 0..545
    const int dn = done_in[b];              // wave-uniform scalar load

    if (!dn) {
        const int rt = tix / NWIN, win = tix - rt * NWIN;
        const int y0 = 10 + rt * 4;             // rows y0..y0+3, all in [10,373]
        const int x0 = 10 + win * 64;           // 10,74,...,330 (win5 masked at 373)

        double pp[NPAR];
#pragma unroll
        for (int i = 0; i < NPAR; i++) pp[i] = p_in[b * NPAR + i];   // uniform
        const double M00 = 1.0 + pp[2], M01 = pp[3], M02 = pp[0];
        const double M10 = pp[4], M11 = 1.0 + pp[5], M12 = pp[1];
        const float* I1b = I1 + (size_t)b * HWPIX * 3;
        const float* I2b = I2 + (size_t)b * HWPIX * 3;

        // one pixel per lane
        const int wid = tid >> 6, lane = tid & 63;
        const int y = y0 + wid;                 // wave-uniform row, <= 373
        const double Y = (double)y;
        const double Bx = M01 * Y + M02;
        const double By = M11 * Y + M12;
        const int x = x0 + lane;
        const double X = (double)x;
        const double xg = fma(M00, X, Bx);
        const double yg = fma(M10, X, By);
        const double gx = rint(xg), gy = rint(yg);   // half-to-even like jnp.round
        const bool ok = (x < WW - DEL) &&
                        (gx >= (double)DEL && gx <= (double)(WW - DEL) &&
                         gy >= (double)DEL && gy <= (double)(HH - DEL));

        float Iw[3];
        if (ok) {
            bicubic3_fast(I2b, xg, yg, Iw);   // taps in-bounds by 'ok'
        } else {
            Iw[0] = 0.f; Iw[1] = 0.f; Iw[2] = 0.f;   // masked anyway (msk=0)
        }

        // I1 neighborhood via coalesced global vector loads (interior-clamped)
        const int xc = min(x, WW - DEL - 1);
        const int pixL = y * WW + xc;
        const float* c = I1b + pixL * 3;
        vf4 u0 = ldv4(c - 3);          // cl0 cl1 cl2 c0
        vf4 u1 = ldv4(c + 1);          // c1 c2 cr0 cr1
        float cr2 = c[5];
        vf4 uu = ldv4(c - WW * 3);     // cu
        vf4 ud = ldv4(c + WW * 3);     // cd

        const float cl[3] = {u0.x, u0.y, u0.z};
        const float cv[3] = {u0.w, u1.x, u1.y};
        const float cr[3] = {u1.z, u1.w, cr2};
        const float cu[3] = {uu.x, uu.y, uu.z};
        const float cd[3] = {ud.x, ud.y, ud.z};

        const float msk = ok ? 1.0f : 0.0f;
        float Af = 0.f, Bf = 0.f, Cf = 0.f, T0f = 0.f, T1f = 0.f;
#pragma unroll
        for (int ch = 0; ch < 3; ch++) {
            const float Ix = (cr[ch] - cl[ch]) * 0.5f;
            const float Iy = (cd[ch] - cu[ch]) * 0.5f;
            const float d = Iw[ch] - cv[ch];
            const float u = d * 20.0f;
            const float w = msk / sqrtf(fmaf(u, u, 1.0f));
            const float wd = w * d;
            T0f = fmaf(Ix, wd, T0f);
            T1f = fmaf(Iy, wd, T1f);
            const float wIx = w * Ix;
            Af = fmaf(wIx, Ix, Af);
            Bf = fmaf(wIx, Iy, Bf);
            Cf = fmaf(w * Iy, Iy, Cf);
        }
        const double T0 = (double)T0f, T1 = (double)T1f;
        const double A = (double)Af, Bd = (double)Bf, Cd = (double)Cf;
        const double XX = X * X;
        double s[13];
        s[0] = T0;  s[1] = T0 * X;
        s[2] = T1;  s[3] = T1 * X;
        s[4] = A;   s[5] = A * X;   s[6] = A * XX;
        s[7] = Bd;  s[8] = Bd * X;  s[9] = Bd * XX;
        s[10] = Cd; s[11] = Cd * X; s[12] = Cd * XX;

        // one shuffle fold (lane+32), then lanes 0..31 dump raw partials to LDS
#pragma unroll
        for (int i = 0; i < 13; i++) s[i] += __shfl_down(s[i], 32, 64);

        if (lane < 32) {
            double* o = scr + ((size_t)(wid * 32 + lane)) * 13;
#pragma unroll
            for (int i = 0; i < 13; i++) o[i] = s[i];
        }
        __syncthreads();

        if (tid < NACC) {
            // component -> (s index, Y power); packed nibble/2-bit tables
            const unsigned long long CLO = 0x9787456454232010ULL;  // cix tid 0..15
            const unsigned long long CHI = 0x00000000abcaba78ULL;  // cix tid 16..23
            const unsigned long long YPW = 0x0000910910910410ULL;  // pw  tid 0..23
            const int cix = (int)(((tid < 16) ? (CLO >> (tid * 4)) : (CHI >> ((tid - 16) * 4))) & 0xF);
            const int pw  = (int)((YPW >> (tid * 2)) & 0x3);
            double acc = 0.0;
            for (int w = 0; w < 4; w++) {
                const double* basep = scr + ((size_t)(w * 32)) * 13 + cix;
                double part = 0.0;
                for (int l = 0; l < 32; l++) part += basep[(size_t)l * 13];
                const double Yw = (double)(y0 + w);
                const double f = (pw == 0) ? 1.0 : ((pw == 1) ? Yw : Yw * Yw);
                acc = fma(f, part, acc);
            }
            const int bkt = tix & (KB_ - 1);
            // returning form: consuming old value forces vmcnt retirement ==
            // RMW committed at the LLC before this block arrives.
            double oldv = unsafeAtomicAdd(&S_out[((size_t)(bkt * BB + b)) * SPS + tid], acc);
            asm volatile("" :: "v"(oldv));
        }
    }

    // ---- one-shot RELAXED hierarchical arrival; unique last block finishes ----
    __syncthreads();                         // S RMWs of this block committed
    if (tid == 0) {
        lastflag = 0;
        const unsigned o1 = __hip_atomic_fetch_add(&c1[tix % L1N], 1u,
                                __ATOMIC_RELAXED, __HIP_MEMORY_SCOPE_AGENT);
        if (o1 == (unsigned)(L1CNT - 1)) {
            const unsigned o2 = __hip_atomic_fetch_add(c2, 1u,
                                    __ATOMIC_RELAXED, __HIP_MEMORY_SCOPE_AGENT);
            if (o2 == (unsigned)(L1N - 1)) lastflag = 1;
        }
    }
    __syncthreads();
    if (lastflag) {
        double* FSUM = SMEMD;                // [8][24]
        if (tid < BB * NACC) {
            const int bt = tid / NACC, a = tid - bt * NACC;
            double sv = 0.0;
#pragma unroll
            for (int k = 0; k < KB_; k++)
                sv += __hip_atomic_load(&S_out[((size_t)(k * BB + bt)) * SPS + a],
                                        __ATOMIC_RELAXED, __HIP_MEMORY_SCOPE_AGENT);
            FSUM[bt * NACC + a] = sv;
        }
        __syncthreads();
        if (tid < BB) {
            const int bt = tid;
            double pc[NPAR], pn[NPAR];
#pragma unroll
            for (int i = 0; i < NPAR; i++) pc[i] = p_in[bt * NPAR + i];
            if (done_in[bt]) {
#pragma unroll
                for (int i = 0; i < NPAR; i++) p_out[bt * NPAR + i] = pc[i];
                done_out[bt] = 1;
            } else {
                int conv;
                solve6_fast(&FSUM[bt * NACC], pc, pn, &conv);
#pragma unroll
                for (int i = 0; i < NPAR; i++) p_out[bt * NPAR + i] = pn[i];
                done_out[bt] = conv;
            }
        }
    }
}

// 2-row x 128-col tiles over the FULL image, ONE pixel per lane.
// 576x8 = 4608 blocks, 13.5 KB LDS -> 8 blocks/CU. Prologue-free: reads pf
// (computed by k_iter(11)'s finisher). Unchanged from the verified R4/R5 form.
extern "C" __global__ __launch_bounds__(256, 8)
void k_final_map(const float* __restrict__ I1, const float* __restrict__ I2,
                 const double* __restrict__ pf_in,
                 float* __restrict__ DI_out, float* __restrict__ Iw_out,
                 double* __restrict__ Sf_part) {
    __shared__ lf4 I2S[NR2F * PITCHF];      // 13536 B
    __shared__ double wsum[4][2];
    const int tid = threadIdx.x;
    const int b = blockIdx.y;
    const int tix = blockIdx.x;             // 0..575
    const int rt = tix / 3, win = tix - rt * 3;
    const int y0 = rt * 2;
    const int x0 = win * 128;
    const int sx0 = x0 - 6;

    double pp[NPAR];
#pragma unroll
    for (int i = 0; i < NPAR; i++) pp[i] = pf_in[b * NPAR + i];   // uniform
    const double M00 = 1.0 + pp[2], M01 = pp[3], M02 = pp[0];
    const double M10 = pp[4], M11 = 1.0 + pp[5], M12 = pp[1];
    const float* I1b = I1 + (size_t)b * HWPIX * 3;
    const float* I2b = I2 + (size_t)b * HWPIX * 3;
    float* DIb = DI_out + (size_t)b * HWPIX * 3;
    float* Iwb = Iw_out + (size_t)b * HWPIX * 3;

    const double ygc = M10 * (double)(x0 + 64) + M11 * ((double)y0 + 0.5) + M12;
    const int r0 = (int)fmin(fmax(floor(ygc) - 2.0, -100000.0), 100000.0);
    for (int i = tid; i < NR2F * WSF; i += 256) {
        const int r = i / WSF, c = i - r * WSF;
        const int gr = min(max(r0 + r, 0), HH - 1);    // clamped staging == clip-to-edge
        const int gc = min(max(sx0 + c, 0), WW - 1);
        I2S[r * PITCHF + c] = ldpx3(I2b, gr * WW + gc);
    }
    __syncthreads();

    const int row = tid >> 7;               // 0..1
    const int x = x0 + (tid & 127);
    const int y = y0 + row;
    const int pix = y * WW + x;

    const double X = (double)x, Yd = (double)y;
    const double xg = fma(M00, X, fma(M01, Yd, M02));
    const double yg = fma(M10, X, fma(M11, Yd, M12));
    const double fx = floor(xg), fy = floor(yg);
    const int xi = (int)fx, yi = (int)fy;
    const float tx = (float)(xg - fx), ty = (float)(yg - fy);
    const int sxi = xi - sx0, syi = yi - r0;
    const bool inwin = (sxi >= 1) && (sxi <= WSF - 3) && (syi >= 1) && (syi <= NR2F - 3);

    float Iwp[3];
    if (inwin) bicubic3_lds<PITCHF>(I2S, sxi, syi, tx, ty, Iwp);
    else       bicubic3_gen(I2b, xg, yg, Iwp);

    const bool v1 = (x >= DEL) && (x < WW - DEL) && (y >= DEL) && (y < HH - DEL);
    const double gx = rint(xg), gy = rint(yg);
    const bool wm = (gx >= (double)DEL && gx <= (double)(WW - DEL) &&
                     gy >= (double)DEL && gy <= (double)(HH - DEL));
    const bool mp = v1 && wm;

    // I1 center (12 B per lane, coalesced)
    const float* cbase = I1b + (size_t)pix * 3;
    const float cv0 = cbase[0], cv1 = cbase[1], cv2 = cbase[2];

    // Iw store (12 B per lane: dwordx2 + dword)
    {
        float* wp = Iwb + (size_t)pix * 3;
        *(f2v*)wp = (f2v){Iwp[0], Iwp[1]};
        wp[2] = Iwp[2];
    }
    double rho_s = 0.0, cnt_s = 0.0;
    {
        const float cvv[3] = {cv0, cv1, cv2};
        float dv[3];
#pragma unroll
        for (int ch = 0; ch < 3; ch++) {
            const float d1 = mp ? (Iwp[ch] - cvv[ch]) : 0.0f;
            dv[ch] = d1;
            if (mp) {
                const float u = d1 * 20.0f;
                rho_s += (double)(0.005f * (sqrtf(fmaf(u, u, 1.0f)) - 1.0f));
            }
        }
        if (mp) cnt_s += 3.0;
        float* dp_ = DIb + (size_t)pix * 3;
        *(f2v*)dp_ = (f2v){dv[0], dv[1]};
        dp_[2] = dv[2];
    }

#pragma unroll
    for (int off = 32; off >= 1; off >>= 1) {
        rho_s += __shfl_down(rho_s, off, 64);
        cnt_s += __shfl_down(cnt_s, off, 64);
    }
    const int wv = tid >> 6, lane = tid & 63;
    if (lane == 0) { wsum[wv][0] = rho_s; wsum[wv][1] = cnt_s; }
    __syncthreads();
    if (tid < 2) {
        double sv = wsum[0][tid] + wsum[1][tid] + wsum[2][tid] + wsum[3][tid];
        const int bkt = blockIdx.x & (KB_ - 1);
        unsafeAtomicAdd(&Sf_part[((size_t)(bkt * BB + b)) * 4 + tid], sv);
    }
}

extern "C" __global__ void k_finish(const double* __restrict__ p_fin,
                                    const double* __restrict__ Sf_part,
                                    float* __restrict__ out) {
    const int tid = threadIdx.x;  // 64 threads
    if (tid < BB * NPAR) out[tid] = (float)p_fin[tid];           // pf
    if (tid >= 48 && tid < 48 + BB) {
        const int b = tid - 48;
        double rs = 0.0, cs = 0.0;
#pragma unroll
        for (int k = 0; k < KB_; k++) {
            rs += Sf_part[((size_t)(k * BB + b)) * 4 + 0];
            cs += Sf_part[((size_t)(k * BB + b)) * 4 + 1];
        }
        out[48 + b] = (float)(rs / fmax(cs, 1.0));               // err
    }
}

extern "C" void kernel_launch(void* const* d_in, const int* in_sizes, int n_in,
                              void* d_out, int out_size, void* d_ws, size_t ws_size,
                              hipStream_t stream) {
    const float* I1 = (const float*)d_in[0];
    const float* I2 = (const float*)d_in[1];
    const float* p0 = (const float*)d_in[2];
    float* out = (float*)d_out;

    // ws layout (8B-aligned):
    // [0)      p_store    (MAXIT+1)*48 doubles = 4992 B   (p[it]; p[12]=pf)
    // [4992)   done       (MAXIT+1)*8 ints     = 416 B
    // [5408)   S_part_all MAXIT*8*8*32 doubles = 196608 B (bucketed, line-padded)
    // [202016) Sf_part    8*8*4 doubles        = 2048 B
    // [204064) cnt        MAXIT*92 uints       = 4416 B   (arrival counters)
    double* p_store = (double*)d_ws;
    int* done_flags = (int*)((char*)d_ws + 4992);
    double* S_part_all = (double*)((char*)d_ws + 5408);
    double* Sf_part = (double*)((char*)d_ws + 202016);
    unsigned int* cnt = (unsigned int*)((char*)d_ws + 204064);

    k_init<<<64, 256, 0, stream>>>(p0, p_store, done_flags, S_part_all, Sf_part, cnt);

    const size_t SIT = (size_t)KB_ * BB * SPS;   // doubles per iteration
    dim3 gridI(NBX, BB), blkI(256);              // 546 x 8 = 4368 blocks
    for (int it = 0; it < MAXIT; it++) {
        k_iter<<<gridI, blkI, 0, stream>>>(I1, I2,
                                           p_store + (size_t)it * BB * NPAR,
                                           done_flags + it * BB,
                                           S_part_all + (size_t)it * SIT,
                                           p_store + (size_t)(it + 1) * BB * NPAR,
                                           done_flags + (it + 1) * BB,
                                           cnt + it * CNTS,
                                           cnt + it * CNTS + L1N);
    }
    // k_iter(11)'s finisher wrote p_store[12] = pf.
    float* DI_out = out + 56;
    float* Iw_out = out + 56 + (size_t)BB * HWPIX * 3;
    dim3 gridF(192 * 3, BB), blkF(256);          // 576 x 8 = 4608 blocks
    k_final_map<<<gridF, blkF, 0, stream>>>(I1, I2,
                                            p_store + (size_t)MAXIT * BB * NPAR,
                                            DI_out, Iw_out, Sf_part);
    k_finish<<<1, 64, 0, stream>>>(p_store + (size_t)MAXIT * BB * NPAR, Sf_part, out);
}